// Round 2
// baseline (1056.408 us; speedup 1.0000x reference)
//
#include <hip/hip_runtime.h>
#include <hip/hip_bf16.h>
#include <math.h>

// Problem constants
constexpr int N = 10000;
constexpr int E = 160000;
constexpr int B = 16;
// H=64, A=8, IN=16, L=2

typedef short bf16x8 __attribute__((ext_vector_type(8)));
typedef float f32x4 __attribute__((ext_vector_type(4)));

__device__ __forceinline__ float silu_f(float x) {
    return x / (1.0f + __expf(-x));
}

// ---------------- K1: embedding h = TP(concat(x,anf), na, W_emb) + b ----------------
__global__ __launch_bounds__(256) void k_embed(
        const float* __restrict__ x, const float* __restrict__ anf,
        const float* __restrict__ na, const float* __restrict__ W,
        const float* __restrict__ b, float* __restrict__ h) {
    int wv = threadIdx.x >> 6;
    int k = threadIdx.x & 63;
    int n = blockIdx.x * 4 + wv;
    float naR[8];
#pragma unroll
    for (int j = 0; j < 8; ++j) naR[j] = na[n * 8 + j];
    float acc = b[k];
#pragma unroll
    for (int i = 0; i < 17; ++i) {
        float xi = (i < 16) ? x[n * 16 + i] : anf[n];
#pragma unroll
        for (int j = 0; j < 8; ++j)
            acc = fmaf(xi * naR[j], W[(i * 8 + j) * 64 + k], acc);
    }
    h[(size_t)n * 64 + k] = acc;
}

// ---------------- K_w2: reorder Wm2[l][i][j][k] -> W2t[l][n=k*8+j][i], bf16 hi/lo split ----------------
__global__ __launch_bounds__(256) void k_w2(
        const float* __restrict__ Wm2,
        __hip_bfloat16* __restrict__ W2hi, __hip_bfloat16* __restrict__ W2lo) {
    int idx = blockIdx.x * 256 + threadIdx.x;   // over 2*512*64 = 65536
    int l = idx >> 15;
    int rem = idx & 32767;
    int n = rem >> 6;           // 0..511
    int i = rem & 63;
    int k = n >> 3, j = n & 7;
    float wv = Wm2[(size_t)l * 32768 + i * 512 + j * 64 + k];
    __hip_bfloat16 hi = __float2bfloat16(wv);
    float lo = wv - __bfloat162float(hi);
    W2hi[idx] = hi;
    W2lo[idx] = __float2bfloat16(lo);
}

// ---------------- K2: per-node P1/P2 precompute for message TP (bf16 output) ----------------
// P layout: P[n][part(2)][j(8)][k(64)]  (1024 bf16 per node)
constexpr int K2_NPB = 16;
__global__ __launch_bounds__(512) void k_precompute(
        const float* __restrict__ h, const float* __restrict__ anf,
        const float* __restrict__ Wm1_l, __hip_bfloat16* __restrict__ P) {
    __shared__ float ha[K2_NPB][66];
    int n0 = blockIdx.x * K2_NPB;
    for (int idx = threadIdx.x; idx < K2_NPB * 65; idx += 512) {
        int nn = idx / 65, i = idx % 65;
        ha[nn][i] = (i < 64) ? h[(size_t)(n0 + nn) * 64 + i] : anf[n0 + nn];
    }
    __syncthreads();
    int o = threadIdx.x;  // o = j*64+k
    float acc1[K2_NPB], acc2[K2_NPB];
#pragma unroll
    for (int nn = 0; nn < K2_NPB; ++nn) { acc1[nn] = 0.f; acc2[nn] = 0.f; }
    for (int i = 0; i < 65; ++i) {
        float w1 = Wm1_l[i * 512 + o];
        float w2 = Wm1_l[(65 + i) * 512 + o];
#pragma unroll
        for (int nn = 0; nn < K2_NPB; ++nn) {
            float a = ha[nn][i];
            acc1[nn] = fmaf(a, w1, acc1[nn]);
            acc2[nn] = fmaf(a, w2, acc2[nn]);
        }
    }
#pragma unroll
    for (int nn = 0; nn < K2_NPB; ++nn) {
        P[(size_t)(n0 + nn) * 1024 + o] = __float2bfloat16(acc1[nn]);
        P[(size_t)(n0 + nn) * 1024 + 512 + o] = __float2bfloat16(acc2[nn]);
    }
}

// ---------------- K3: edge kernel: m1 (via P), silu -> bf16 m; MFMA m2 TP; silu; scatter ----------------
constexpr int MS = 72;  // m_s row stride in bf16 elems (144 B = 36 banks, breaks pow2)
__global__ __launch_bounds__(256, 3) void k_edge(
        const int* __restrict__ eidx, const float* __restrict__ ea,
        const float* __restrict__ amf, const __hip_bfloat16* __restrict__ P,
        const float* __restrict__ Wm1_l, const float* __restrict__ bm1_l,
        const __hip_bfloat16* __restrict__ W2hi, const __hip_bfloat16* __restrict__ W2lo,
        const float* __restrict__ bm2_l, float* __restrict__ agg) {
    __shared__ __align__(16) __hip_bfloat16 m_s[128 * MS];
    __shared__ float ea_s[128][9];
    __shared__ float amf_s[128];
    __shared__ int src_s[128], dst_s[128];
    __shared__ float w130_s[512];
    __shared__ float bm1_s[64], bm2_s[64];
    int tid = threadIdx.x;
    int l = tid & 63, w = tid >> 6;
    int e0 = blockIdx.x * 128;
    for (int idx = tid; idx < 128; idx += 256) {
        src_s[idx] = eidx[e0 + idx];
        dst_s[idx] = eidx[E + e0 + idx];
        amf_s[idx] = amf[e0 + idx];
    }
    for (int idx = tid; idx < 1024; idx += 256) ea_s[idx >> 3][idx & 7] = ea[(size_t)e0 * 8 + idx];
    for (int idx = tid; idx < 512; idx += 256) w130_s[idx] = Wm1_l[130 * 512 + idx];
    if (tid < 64) { bm1_s[tid] = bm1_l[tid]; bm2_s[tid] = bm2_l[tid]; }
    __syncthreads();

    // ---- phase 1: m = bf16(silu(m1)) for this wave's 32 edges ----
    int k = l;
    float bm1k = bm1_s[k];
#pragma unroll 4
    for (int q = 0; q < 32; ++q) {
        int le = w * 32 + q;
        const __hip_bfloat16* P1 = P + (size_t)dst_s[le] * 1024 + k;
        const __hip_bfloat16* P2 = P + (size_t)src_s[le] * 1024 + 512 + k;
        float amfe = amf_s[le];
        float macc = bm1k;
#pragma unroll
        for (int j = 0; j < 8; ++j) {
            float s = __bfloat162float(P1[j * 64]) + __bfloat162float(P2[j * 64]) +
                      amfe * w130_s[j * 64 + k];
            macc = fmaf(ea_s[le][j], s, macc);
        }
        m_s[le * MS + k] = __float2bfloat16(silu_f(macc));
    }
    __syncthreads();

    // ---- phase 2: MFMA  C[e][n] = sum_i m[e][i] * W2t[n][i],  n = k*8+j ----
    int e0w = w * 32;
    int col = l & 15, quad = l >> 4;
    bf16x8 aF[2][2];
#pragma unroll
    for (int mt = 0; mt < 2; ++mt)
#pragma unroll
        for (int kk = 0; kk < 2; ++kk)
            aF[mt][kk] = *(const bf16x8*)&m_s[(e0w + mt * 16 + col) * MS + kk * 32 + quad * 8];

    float eaR[2][4];
    int dstR[2][4];
#pragma unroll
    for (int mt = 0; mt < 2; ++mt)
#pragma unroll
        for (int r = 0; r < 4; ++r) {
            int e_ = e0w + mt * 16 + quad * 4 + r;
            eaR[mt][r] = ea_s[e_][l & 7];
            dstR[mt][r] = dst_s[e_];
        }

    bool writer = (l & 7) == 0;
    int kv0 = (l >> 3) & 1;
    f32x4 zero4 = {0.f, 0.f, 0.f, 0.f};
    for (int c = 0; c < 4; ++c) {
        f32x4 acc[2][8];
#pragma unroll
        for (int mt = 0; mt < 2; ++mt)
#pragma unroll
            for (int t = 0; t < 8; ++t) acc[mt][t] = zero4;
#pragma unroll
        for (int t = 0; t < 8; ++t) {
            int nrow = c * 128 + t * 16 + col;
            const __hip_bfloat16* bph = W2hi + nrow * 64 + quad * 8;
            const __hip_bfloat16* bpl = W2lo + nrow * 64 + quad * 8;
            bf16x8 bh0 = *(const bf16x8*)(bph);
            bf16x8 bh1 = *(const bf16x8*)(bph + 32);
            bf16x8 bl0 = *(const bf16x8*)(bpl);
            bf16x8 bl1 = *(const bf16x8*)(bpl + 32);
#pragma unroll
            for (int mt = 0; mt < 2; ++mt) {
                acc[mt][t] = __builtin_amdgcn_mfma_f32_16x16x32_bf16(aF[mt][0], bh0, acc[mt][t], 0, 0, 0);
                acc[mt][t] = __builtin_amdgcn_mfma_f32_16x16x32_bf16(aF[mt][1], bh1, acc[mt][t], 0, 0, 0);
                acc[mt][t] = __builtin_amdgcn_mfma_f32_16x16x32_bf16(aF[mt][0], bl0, acc[mt][t], 0, 0, 0);
                acc[mt][t] = __builtin_amdgcn_mfma_f32_16x16x32_bf16(aF[mt][1], bl1, acc[mt][t], 0, 0, 0);
            }
        }
        // epilogue: multiply by ea_j, butterfly-sum over j (lanes xor 1,2,4), silu, atomic scatter
#pragma unroll
        for (int t = 0; t < 8; ++t) {
#pragma unroll
            for (int mt = 0; mt < 2; ++mt) {
#pragma unroll
                for (int r = 0; r < 4; ++r) {
                    float v = acc[mt][t][r] * eaR[mt][r];
                    v += __shfl_xor(v, 1, 64);
                    v += __shfl_xor(v, 2, 64);
                    v += __shfl_xor(v, 4, 64);
                    if (writer) {
                        int kk2 = c * 16 + t * 2 + kv0;
                        float m2v = silu_f(bm2_s[kk2] + v);
                        atomicAdd(&agg[(size_t)dstR[mt][r] * 64 + kk2], m2v);
                    }
                }
            }
        }
    }
}

// ---------------- K4: node update u1=silu(TP(xin,na,Wu1)), u2=TP(u1,na,Wu2), h+=u2 ----------------
constexpr int K4_NPB = 8;
__global__ __launch_bounds__(512) void k_update(
        const float* __restrict__ anf, const float* __restrict__ na,
        const float* __restrict__ agg,
        const float* __restrict__ Wu1_l, const float* __restrict__ bu1_l,
        const float* __restrict__ Wu2_l, const float* __restrict__ bu2_l,
        float* __restrict__ h) {
    __shared__ __align__(16) float xin[K4_NPB][132];
    __shared__ float C[K4_NPB][512];
    __shared__ __align__(16) float u_s[K4_NPB][64];
    __shared__ float na_s[K4_NPB][8];
    int tid = threadIdx.x;
    int n0 = blockIdx.x * K4_NPB;
    for (int idx = tid; idx < K4_NPB * 8; idx += 512) na_s[idx >> 3][idx & 7] = na[(size_t)n0 * 8 + idx];
    for (int idx = tid; idx < K4_NPB * 132; idx += 512) {
        int nn = idx / 132, i = idx % 132;
        int n = n0 + nn;
        float v = 0.f;
        if (i < 64) v = h[(size_t)n * 64 + i];
        else if (i == 64) v = anf[n];
        else if (i < 129) v = agg[(size_t)n * 64 + (i - 65)];
        xin[nn][i] = v;
    }
    __syncthreads();
    int o = tid;
    {
        float acc[K4_NPB];
#pragma unroll
        for (int nn = 0; nn < K4_NPB; ++nn) acc[nn] = 0.f;
        for (int i4 = 0; i4 < 32; ++i4) {
            float w0 = Wu1_l[(i4 * 4 + 0) * 512 + o];
            float w1 = Wu1_l[(i4 * 4 + 1) * 512 + o];
            float w2 = Wu1_l[(i4 * 4 + 2) * 512 + o];
            float w3 = Wu1_l[(i4 * 4 + 3) * 512 + o];
#pragma unroll
            for (int nn = 0; nn < K4_NPB; ++nn) {
                float4 xv = *(const float4*)&xin[nn][i4 * 4];
                acc[nn] = fmaf(xv.x, w0, acc[nn]);
                acc[nn] = fmaf(xv.y, w1, acc[nn]);
                acc[nn] = fmaf(xv.z, w2, acc[nn]);
                acc[nn] = fmaf(xv.w, w3, acc[nn]);
            }
        }
        float w128 = Wu1_l[128 * 512 + o];
#pragma unroll
        for (int nn = 0; nn < K4_NPB; ++nn) {
            acc[nn] = fmaf(xin[nn][128], w128, acc[nn]);
            C[nn][o] = acc[nn];
        }
    }
    __syncthreads();
    {
        int nn = tid >> 6, kk = tid & 63;
        float v = bu1_l[kk];
#pragma unroll
        for (int j = 0; j < 8; ++j) v = fmaf(na_s[nn][j], C[nn][j * 64 + kk], v);
        u_s[nn][kk] = silu_f(v);
    }
    __syncthreads();
    {
        float acc[K4_NPB];
#pragma unroll
        for (int nn = 0; nn < K4_NPB; ++nn) acc[nn] = 0.f;
        for (int i4 = 0; i4 < 16; ++i4) {
            float w0 = Wu2_l[(i4 * 4 + 0) * 512 + o];
            float w1 = Wu2_l[(i4 * 4 + 1) * 512 + o];
            float w2 = Wu2_l[(i4 * 4 + 2) * 512 + o];
            float w3 = Wu2_l[(i4 * 4 + 3) * 512 + o];
#pragma unroll
            for (int nn = 0; nn < K4_NPB; ++nn) {
                float4 xv = *(const float4*)&u_s[nn][i4 * 4];
                acc[nn] = fmaf(xv.x, w0, acc[nn]);
                acc[nn] = fmaf(xv.y, w1, acc[nn]);
                acc[nn] = fmaf(xv.z, w2, acc[nn]);
                acc[nn] = fmaf(xv.w, w3, acc[nn]);
            }
        }
        __syncthreads();
#pragma unroll
        for (int nn = 0; nn < K4_NPB; ++nn) C[nn][o] = acc[nn];
    }
    __syncthreads();
    {
        int nn = tid >> 6, kk = tid & 63;
        float v = bu2_l[kk];
#pragma unroll
        for (int j = 0; j < 8; ++j) v = fmaf(na_s[nn][j], C[nn][j * 64 + kk], v);
        h[(size_t)(n0 + nn) * 64 + kk] += v;
    }
}

// ---------------- K6: prepool p=silu(TP(h,na,Wp1)); p2=TP(p,na,Wp2); pooled atomics ----------------
__global__ __launch_bounds__(512) void k_prepool(
        const float* __restrict__ h, const float* __restrict__ na,
        const int* __restrict__ batch,
        const float* __restrict__ Wp1, const float* __restrict__ bp1,
        const float* __restrict__ Wp2, const float* __restrict__ bp2,
        float* __restrict__ pooled, float* __restrict__ cnt) {
    __shared__ __align__(16) float xin[K4_NPB][64];
    __shared__ float C[K4_NPB][512];
    __shared__ __align__(16) float u_s[K4_NPB][64];
    __shared__ float na_s[K4_NPB][8];
    int tid = threadIdx.x;
    int n0 = blockIdx.x * K4_NPB;
    for (int idx = tid; idx < K4_NPB * 8; idx += 512) na_s[idx >> 3][idx & 7] = na[(size_t)n0 * 8 + idx];
    for (int idx = tid; idx < K4_NPB * 64; idx += 512) (&xin[0][0])[idx] = h[(size_t)n0 * 64 + idx];
    __syncthreads();
    int o = tid;
    {
        float acc[K4_NPB];
#pragma unroll
        for (int nn = 0; nn < K4_NPB; ++nn) acc[nn] = 0.f;
        for (int i4 = 0; i4 < 16; ++i4) {
            float w0 = Wp1[(i4 * 4 + 0) * 512 + o];
            float w1 = Wp1[(i4 * 4 + 1) * 512 + o];
            float w2 = Wp1[(i4 * 4 + 2) * 512 + o];
            float w3 = Wp1[(i4 * 4 + 3) * 512 + o];
#pragma unroll
            for (int nn = 0; nn < K4_NPB; ++nn) {
                float4 xv = *(const float4*)&xin[nn][i4 * 4];
                acc[nn] = fmaf(xv.x, w0, acc[nn]);
                acc[nn] = fmaf(xv.y, w1, acc[nn]);
                acc[nn] = fmaf(xv.z, w2, acc[nn]);
                acc[nn] = fmaf(xv.w, w3, acc[nn]);
            }
        }
#pragma unroll
        for (int nn = 0; nn < K4_NPB; ++nn) C[nn][o] = acc[nn];
    }
    __syncthreads();
    {
        int nn = tid >> 6, kk = tid & 63;
        float v = bp1[kk];
#pragma unroll
        for (int j = 0; j < 8; ++j) v = fmaf(na_s[nn][j], C[nn][j * 64 + kk], v);
        u_s[nn][kk] = silu_f(v);
    }
    __syncthreads();
    {
        float acc[K4_NPB];
#pragma unroll
        for (int nn = 0; nn < K4_NPB; ++nn) acc[nn] = 0.f;
        for (int i4 = 0; i4 < 16; ++i4) {
            float w0 = Wp2[(i4 * 4 + 0) * 512 + o];
            float w1 = Wp2[(i4 * 4 + 1) * 512 + o];
            float w2 = Wp2[(i4 * 4 + 2) * 512 + o];
            float w3 = Wp2[(i4 * 4 + 3) * 512 + o];
#pragma unroll
            for (int nn = 0; nn < K4_NPB; ++nn) {
                float4 xv = *(const float4*)&u_s[nn][i4 * 4];
                acc[nn] = fmaf(xv.x, w0, acc[nn]);
                acc[nn] = fmaf(xv.y, w1, acc[nn]);
                acc[nn] = fmaf(xv.z, w2, acc[nn]);
                acc[nn] = fmaf(xv.w, w3, acc[nn]);
            }
        }
        __syncthreads();
#pragma unroll
        for (int nn = 0; nn < K4_NPB; ++nn) C[nn][o] = acc[nn];
    }
    __syncthreads();
    {
        int nn = tid >> 6, kk = tid & 63;
        int n = n0 + nn;
        float v = bp2[kk];
#pragma unroll
        for (int j = 0; j < 8; ++j) v = fmaf(na_s[nn][j], C[nn][j * 64 + kk], v);
        int bb = batch[n];
        atomicAdd(&pooled[bb * 64 + kk], v);
        if (kk == 0) atomicAdd(&cnt[bb], 1.0f);
    }
}

// ---------------- K7: mean pool finish + final MLP ----------------
__global__ __launch_bounds__(1024) void k_final(
        const float* __restrict__ pooled, const float* __restrict__ cnt,
        const float* __restrict__ Wq1, const float* __restrict__ bq1,
        const float* __restrict__ Wq2, const float* __restrict__ bq2,
        float* __restrict__ out) {
    __shared__ float g[16][64];
    int b = threadIdx.x >> 6, k = threadIdx.x & 63;
    g[b][k] = pooled[b * 64 + k] / fmaxf(cnt[b], 1.0f);
    __syncthreads();
    float acc = bq1[k];
#pragma unroll
    for (int i = 0; i < 64; ++i) acc = fmaf(g[b][i], Wq1[i * 64 + k], acc);
    float v = silu_f(acc) * Wq2[k];
#pragma unroll
    for (int off = 32; off > 0; off >>= 1) v += __shfl_down(v, off, 64);
    if (k == 0) out[b] = v + bq2[0];
}

extern "C" void kernel_launch(void* const* d_in, const int* in_sizes, int n_in,
                              void* d_out, int out_size, void* d_ws, size_t ws_size,
                              hipStream_t stream) {
    const float* x    = (const float*)d_in[0];
    const int*   eidx = (const int*)  d_in[1];
    const float* ea   = (const float*)d_in[2];
    const float* na   = (const float*)d_in[3];
    const float* amf  = (const float*)d_in[4];
    const float* anf  = (const float*)d_in[5];
    const int*   batch= (const int*)  d_in[6];
    const float* W_emb= (const float*)d_in[7];
    const float* b_emb= (const float*)d_in[8];
    const float* Wm1  = (const float*)d_in[9];
    const float* bm1  = (const float*)d_in[10];
    const float* Wm2  = (const float*)d_in[11];
    const float* bm2  = (const float*)d_in[12];
    const float* Wu1  = (const float*)d_in[13];
    const float* bu1  = (const float*)d_in[14];
    const float* Wu2  = (const float*)d_in[15];
    const float* bu2  = (const float*)d_in[16];
    const float* Wp1  = (const float*)d_in[17];
    const float* bp1  = (const float*)d_in[18];
    const float* Wp2  = (const float*)d_in[19];
    const float* bp2  = (const float*)d_in[20];
    const float* Wq1  = (const float*)d_in[21];
    const float* bq1  = (const float*)d_in[22];
    const float* Wq2  = (const float*)d_in[23];
    const float* bq2  = (const float*)d_in[24];

    float* ws = (float*)d_ws;
    float* h      = ws;                         // N*64 fp32
    float* agg    = h + (size_t)N * 64;         // N*64 fp32
    float* pooled = agg + (size_t)N * 64;       // B*64
    float* cnt    = pooled + B * 64;            // B
    __hip_bfloat16* Pb   = (__hip_bfloat16*)(cnt + 64);          // N*1024 bf16 (64 floats pad for align)
    __hip_bfloat16* W2hi = Pb + (size_t)N * 1024;                // 2*512*64 bf16
    __hip_bfloat16* W2lo = W2hi + 2 * 512 * 64;

    k_embed<<<N / 4, 256, 0, stream>>>(x, anf, na, W_emb, b_emb, h);
    k_w2<<<256, 256, 0, stream>>>(Wm2, W2hi, W2lo);
    for (int l = 0; l < 2; ++l) {
        hipMemsetAsync(agg, 0, (size_t)N * 64 * sizeof(float), stream);
        k_precompute<<<N / K2_NPB, 512, 0, stream>>>(h, anf, Wm1 + (size_t)l * 131 * 512, Pb);
        k_edge<<<E / 128, 256, 0, stream>>>(eidx, ea, amf, Pb,
                                            Wm1 + (size_t)l * 131 * 512, bm1 + l * 64,
                                            W2hi + (size_t)l * 32768, W2lo + (size_t)l * 32768,
                                            bm2 + l * 64, agg);
        k_update<<<N / K4_NPB, 512, 0, stream>>>(anf, na, agg,
                                                 Wu1 + (size_t)l * 129 * 512, bu1 + l * 64,
                                                 Wu2 + (size_t)l * 64 * 512, bu2 + l * 64, h);
    }
    hipMemsetAsync(pooled, 0, (size_t)(B * 64 + B) * sizeof(float), stream);
    k_prepool<<<N / K4_NPB, 512, 0, stream>>>(h, na, batch, Wp1, bp1, Wp2, bp2, pooled, cnt);
    k_final<<<1, 1024, 0, stream>>>(pooled, cnt, Wq1, bq1, Wq2, bq2, (float*)d_out);
}

// Round 3
// 640.478 us; speedup vs baseline: 1.6494x; 1.6494x over previous
//
#include <hip/hip_runtime.h>
#include <hip/hip_bf16.h>
#include <math.h>

// Problem constants
constexpr int N = 10000;
constexpr int E = 160000;
constexpr int B = 16;
// H=64, A=8, IN=16, L=2

typedef short bf16x8 __attribute__((ext_vector_type(8)));
typedef float f32x4 __attribute__((ext_vector_type(4)));

__device__ __forceinline__ float silu_f(float x) {
    return x / (1.0f + __expf(-x));
}

// ---------------- K1: embedding h = TP(concat(x,anf), na, W_emb) + b ----------------
__global__ __launch_bounds__(256) void k_embed(
        const float* __restrict__ x, const float* __restrict__ anf,
        const float* __restrict__ na, const float* __restrict__ W,
        const float* __restrict__ b, float* __restrict__ h) {
    int wv = threadIdx.x >> 6;
    int k = threadIdx.x & 63;
    int n = blockIdx.x * 4 + wv;
    float naR[8];
#pragma unroll
    for (int j = 0; j < 8; ++j) naR[j] = na[n * 8 + j];
    float acc = b[k];
#pragma unroll
    for (int i = 0; i < 17; ++i) {
        float xi = (i < 16) ? x[n * 16 + i] : anf[n];
#pragma unroll
        for (int j = 0; j < 8; ++j)
            acc = fmaf(xi * naR[j], W[(i * 8 + j) * 64 + k], acc);
    }
    h[(size_t)n * 64 + k] = acc;
}

// ---------------- K_w2: Wm2[l][i][j][k] -> W2z[l][kk][nt][c][q][j], bf16 hi/lo ----------------
// B-operand layout for z-GEMM: B[kidx=q*8+j][n=nt*16+c] = W2flat[ij=kk*32+q*8+j][k=nt*16+c]
__global__ __launch_bounds__(256) void k_w2(
        const float* __restrict__ Wm2,
        __hip_bfloat16* __restrict__ W2hi, __hip_bfloat16* __restrict__ W2lo) {
    int idx = blockIdx.x * 256 + threadIdx.x;   // over 2*16*4*16*4*8 = 65536
    int l = idx >> 15;
    int rem = idx & 32767;
    int kk = rem >> 11;
    int nt = (rem >> 9) & 3;
    int c  = (rem >> 5) & 15;
    int q  = (rem >> 3) & 3;
    int j  = rem & 7;
    int i = kk * 4 + q;
    int k = nt * 16 + c;
    float wv = Wm2[(size_t)l * 32768 + i * 512 + j * 64 + k];
    __hip_bfloat16 hi = __float2bfloat16(wv);
    W2hi[idx] = hi;
    W2lo[idx] = __float2bfloat16(wv - __bfloat162float(hi));
}

// ---------------- K2: per-node P1/P2 precompute for message TP (bf16 output) ----------------
// P layout: P[n][part(2)][j(8)][k(64)]  (1024 bf16 per node)
constexpr int K2_NPB = 16;
__global__ __launch_bounds__(512) void k_precompute(
        const float* __restrict__ h, const float* __restrict__ anf,
        const float* __restrict__ Wm1_l, __hip_bfloat16* __restrict__ P) {
    __shared__ float ha[K2_NPB][66];
    int n0 = blockIdx.x * K2_NPB;
    for (int idx = threadIdx.x; idx < K2_NPB * 65; idx += 512) {
        int nn = idx / 65, i = idx % 65;
        ha[nn][i] = (i < 64) ? h[(size_t)(n0 + nn) * 64 + i] : anf[n0 + nn];
    }
    __syncthreads();
    int o = threadIdx.x;  // o = j*64+k
    float acc1[K2_NPB], acc2[K2_NPB];
#pragma unroll
    for (int nn = 0; nn < K2_NPB; ++nn) { acc1[nn] = 0.f; acc2[nn] = 0.f; }
    for (int i = 0; i < 65; ++i) {
        float w1 = Wm1_l[i * 512 + o];
        float w2 = Wm1_l[(65 + i) * 512 + o];
#pragma unroll
        for (int nn = 0; nn < K2_NPB; ++nn) {
            float a = ha[nn][i];
            acc1[nn] = fmaf(a, w1, acc1[nn]);
            acc2[nn] = fmaf(a, w2, acc2[nn]);
        }
    }
#pragma unroll
    for (int nn = 0; nn < K2_NPB; ++nn) {
        P[(size_t)(n0 + nn) * 1024 + o] = __float2bfloat16(acc1[nn]);
        P[(size_t)(n0 + nn) * 1024 + 512 + o] = __float2bfloat16(acc2[nn]);
    }
}

// ---------------- K3: edge kernel: m1 (via P), silu -> bf16 m; z-GEMM MFMA m2; silu; scatter ----------------
constexpr int MS = 72;  // m_s row stride in bf16 elems (144 B = 36 banks, breaks pow2)
__global__ __launch_bounds__(256, 3) void k_edge(
        const int* __restrict__ eidx, const float* __restrict__ ea,
        const float* __restrict__ amf, const __hip_bfloat16* __restrict__ P,
        const float* __restrict__ Wm1_l, const float* __restrict__ bm1_l,
        const __hip_bfloat16* __restrict__ W2hi, const __hip_bfloat16* __restrict__ W2lo,
        const float* __restrict__ bm2_l, float* __restrict__ agg) {
    __shared__ __align__(16) __hip_bfloat16 m_s[128 * MS];
    __shared__ float ea_s[128][9];
    __shared__ float amf_s[128];
    __shared__ int src_s[128], dst_s[128];
    __shared__ float w130_s[512];
    __shared__ float bm1_s[64], bm2_s[64];
    int tid = threadIdx.x;
    int l = tid & 63, w = tid >> 6;
    int e0 = blockIdx.x * 128;
    for (int idx = tid; idx < 128; idx += 256) {
        src_s[idx] = eidx[e0 + idx];
        dst_s[idx] = eidx[E + e0 + idx];
        amf_s[idx] = amf[e0 + idx];
    }
    for (int idx = tid; idx < 1024; idx += 256) ea_s[idx >> 3][idx & 7] = ea[(size_t)e0 * 8 + idx];
    for (int idx = tid; idx < 512; idx += 256) w130_s[idx] = Wm1_l[130 * 512 + idx];
    if (tid < 64) { bm1_s[tid] = bm1_l[tid]; bm2_s[tid] = bm2_l[tid]; }
    __syncthreads();

    // ---- phase 1: m = bf16(silu(m1)) for this wave's 32 edges ----
    int k = l;
    float bm1k = bm1_s[k];
#pragma unroll 4
    for (int q = 0; q < 32; ++q) {
        int le = w * 32 + q;
        const __hip_bfloat16* P1 = P + (size_t)dst_s[le] * 1024 + k;
        const __hip_bfloat16* P2 = P + (size_t)src_s[le] * 1024 + 512 + k;
        float amfe = amf_s[le];
        float macc = bm1k;
#pragma unroll
        for (int j = 0; j < 8; ++j) {
            float s = __bfloat162float(P1[j * 64]) + __bfloat162float(P2[j * 64]) +
                      amfe * w130_s[j * 64 + k];
            macc = fmaf(ea_s[le][j], s, macc);
        }
        m_s[le * MS + k] = __float2bfloat16(silu_f(macc));
    }
    __syncthreads();

    // ---- phase 2: z-GEMM  D[e][kd] = sum_ij (m[e][i]*ea[e][j]) * W2flat[ij][kd] ----
    int c16 = l & 15, q = l >> 4;
    int e0w = w * 32;
    // ea vectors for this lane's A-row edges (row m = lane&15)
    float eaA[2][8];
#pragma unroll
    for (int mt = 0; mt < 2; ++mt)
#pragma unroll
        for (int j = 0; j < 8; ++j) eaA[mt][j] = ea_s[e0w + mt * 16 + c16][j];

    f32x4 acc[2][4];
    f32x4 zero4 = {0.f, 0.f, 0.f, 0.f};
#pragma unroll
    for (int mt = 0; mt < 2; ++mt)
#pragma unroll
        for (int nt = 0; nt < 4; ++nt) acc[mt][nt] = zero4;

    int lofs = (c16 * 4 + q) * 8;
#pragma unroll 2
    for (int kk = 0; kk < 16; ++kk) {
        bf16x8 bh[4], bl[4];
#pragma unroll
        for (int nt = 0; nt < 4; ++nt) {
            int off = (kk * 4 + nt) * 512 + lofs;
            bh[nt] = *(const bf16x8*)(W2hi + off);
            bl[nt] = *(const bf16x8*)(W2lo + off);
        }
#pragma unroll
        for (int mt = 0; mt < 2; ++mt) {
            float mv = __bfloat162float(m_s[(e0w + mt * 16 + c16) * MS + kk * 4 + q]);
            union { bf16x8 v; __hip_bfloat16 h[8]; } au;
#pragma unroll
            for (int j = 0; j < 8; ++j) au.h[j] = __float2bfloat16(mv * eaA[mt][j]);
#pragma unroll
            for (int nt = 0; nt < 4; ++nt) {
                acc[mt][nt] = __builtin_amdgcn_mfma_f32_16x16x32_bf16(au.v, bh[nt], acc[mt][nt], 0, 0, 0);
                acc[mt][nt] = __builtin_amdgcn_mfma_f32_16x16x32_bf16(au.v, bl[nt], acc[mt][nt], 0, 0, 0);
            }
        }
    }
    // ---- epilogue: D row = edge (q*4+r), col = kdim (nt*16+c16); coalesced 64B atomics ----
#pragma unroll
    for (int mt = 0; mt < 2; ++mt)
#pragma unroll
        for (int nt = 0; nt < 4; ++nt) {
            int kd = nt * 16 + c16;
            float bias = bm2_s[kd];
#pragma unroll
            for (int r = 0; r < 4; ++r) {
                int e = e0w + mt * 16 + q * 4 + r;
                float v = silu_f(bias + acc[mt][nt][r]);
                atomicAdd(&agg[(size_t)dst_s[e] * 64 + kd], v);
            }
        }
}

// ---------------- K4: node update u1=silu(TP(xin,na,Wu1)), u2=TP(u1,na,Wu2), h+=u2 ----------------
constexpr int K4_NPB = 8;
__global__ __launch_bounds__(512) void k_update(
        const float* __restrict__ anf, const float* __restrict__ na,
        const float* __restrict__ agg,
        const float* __restrict__ Wu1_l, const float* __restrict__ bu1_l,
        const float* __restrict__ Wu2_l, const float* __restrict__ bu2_l,
        float* __restrict__ h) {
    __shared__ __align__(16) float xin[K4_NPB][132];
    __shared__ float C[K4_NPB][512];
    __shared__ __align__(16) float u_s[K4_NPB][64];
    __shared__ float na_s[K4_NPB][8];
    int tid = threadIdx.x;
    int n0 = blockIdx.x * K4_NPB;
    for (int idx = tid; idx < K4_NPB * 8; idx += 512) na_s[idx >> 3][idx & 7] = na[(size_t)n0 * 8 + idx];
    for (int idx = tid; idx < K4_NPB * 132; idx += 512) {
        int nn = idx / 132, i = idx % 132;
        int n = n0 + nn;
        float v = 0.f;
        if (i < 64) v = h[(size_t)n * 64 + i];
        else if (i == 64) v = anf[n];
        else if (i < 129) v = agg[(size_t)n * 64 + (i - 65)];
        xin[nn][i] = v;
    }
    __syncthreads();
    int o = tid;
    {
        float acc[K4_NPB];
#pragma unroll
        for (int nn = 0; nn < K4_NPB; ++nn) acc[nn] = 0.f;
        for (int i4 = 0; i4 < 32; ++i4) {
            float w0 = Wu1_l[(i4 * 4 + 0) * 512 + o];
            float w1 = Wu1_l[(i4 * 4 + 1) * 512 + o];
            float w2 = Wu1_l[(i4 * 4 + 2) * 512 + o];
            float w3 = Wu1_l[(i4 * 4 + 3) * 512 + o];
#pragma unroll
            for (int nn = 0; nn < K4_NPB; ++nn) {
                float4 xv = *(const float4*)&xin[nn][i4 * 4];
                acc[nn] = fmaf(xv.x, w0, acc[nn]);
                acc[nn] = fmaf(xv.y, w1, acc[nn]);
                acc[nn] = fmaf(xv.z, w2, acc[nn]);
                acc[nn] = fmaf(xv.w, w3, acc[nn]);
            }
        }
        float w128 = Wu1_l[128 * 512 + o];
#pragma unroll
        for (int nn = 0; nn < K4_NPB; ++nn) {
            acc[nn] = fmaf(xin[nn][128], w128, acc[nn]);
            C[nn][o] = acc[nn];
        }
    }
    __syncthreads();
    {
        int nn = tid >> 6, kk = tid & 63;
        float v = bu1_l[kk];
#pragma unroll
        for (int j = 0; j < 8; ++j) v = fmaf(na_s[nn][j], C[nn][j * 64 + kk], v);
        u_s[nn][kk] = silu_f(v);
    }
    __syncthreads();
    {
        float acc[K4_NPB];
#pragma unroll
        for (int nn = 0; nn < K4_NPB; ++nn) acc[nn] = 0.f;
        for (int i4 = 0; i4 < 16; ++i4) {
            float w0 = Wu2_l[(i4 * 4 + 0) * 512 + o];
            float w1 = Wu2_l[(i4 * 4 + 1) * 512 + o];
            float w2 = Wu2_l[(i4 * 4 + 2) * 512 + o];
            float w3 = Wu2_l[(i4 * 4 + 3) * 512 + o];
#pragma unroll
            for (int nn = 0; nn < K4_NPB; ++nn) {
                float4 xv = *(const float4*)&u_s[nn][i4 * 4];
                acc[nn] = fmaf(xv.x, w0, acc[nn]);
                acc[nn] = fmaf(xv.y, w1, acc[nn]);
                acc[nn] = fmaf(xv.z, w2, acc[nn]);
                acc[nn] = fmaf(xv.w, w3, acc[nn]);
            }
        }
        __syncthreads();
#pragma unroll
        for (int nn = 0; nn < K4_NPB; ++nn) C[nn][o] = acc[nn];
    }
    __syncthreads();
    {
        int nn = tid >> 6, kk = tid & 63;
        float v = bu2_l[kk];
#pragma unroll
        for (int j = 0; j < 8; ++j) v = fmaf(na_s[nn][j], C[nn][j * 64 + kk], v);
        h[(size_t)(n0 + nn) * 64 + kk] += v;
    }
}

// ---------------- K6: prepool p=silu(TP(h,na,Wp1)); p2=TP(p,na,Wp2); pooled atomics ----------------
__global__ __launch_bounds__(512) void k_prepool(
        const float* __restrict__ h, const float* __restrict__ na,
        const int* __restrict__ batch,
        const float* __restrict__ Wp1, const float* __restrict__ bp1,
        const float* __restrict__ Wp2, const float* __restrict__ bp2,
        float* __restrict__ pooled, float* __restrict__ cnt) {
    __shared__ __align__(16) float xin[K4_NPB][64];
    __shared__ float C[K4_NPB][512];
    __shared__ __align__(16) float u_s[K4_NPB][64];
    __shared__ float na_s[K4_NPB][8];
    int tid = threadIdx.x;
    int n0 = blockIdx.x * K4_NPB;
    for (int idx = tid; idx < K4_NPB * 8; idx += 512) na_s[idx >> 3][idx & 7] = na[(size_t)n0 * 8 + idx];
    for (int idx = tid; idx < K4_NPB * 64; idx += 512) (&xin[0][0])[idx] = h[(size_t)n0 * 64 + idx];
    __syncthreads();
    int o = tid;
    {
        float acc[K4_NPB];
#pragma unroll
        for (int nn = 0; nn < K4_NPB; ++nn) acc[nn] = 0.f;
        for (int i4 = 0; i4 < 16; ++i4) {
            float w0 = Wp1[(i4 * 4 + 0) * 512 + o];
            float w1 = Wp1[(i4 * 4 + 1) * 512 + o];
            float w2 = Wp1[(i4 * 4 + 2) * 512 + o];
            float w3 = Wp1[(i4 * 4 + 3) * 512 + o];
#pragma unroll
            for (int nn = 0; nn < K4_NPB; ++nn) {
                float4 xv = *(const float4*)&xin[nn][i4 * 4];
                acc[nn] = fmaf(xv.x, w0, acc[nn]);
                acc[nn] = fmaf(xv.y, w1, acc[nn]);
                acc[nn] = fmaf(xv.z, w2, acc[nn]);
                acc[nn] = fmaf(xv.w, w3, acc[nn]);
            }
        }
#pragma unroll
        for (int nn = 0; nn < K4_NPB; ++nn) C[nn][o] = acc[nn];
    }
    __syncthreads();
    {
        int nn = tid >> 6, kk = tid & 63;
        float v = bp1[kk];
#pragma unroll
        for (int j = 0; j < 8; ++j) v = fmaf(na_s[nn][j], C[nn][j * 64 + kk], v);
        u_s[nn][kk] = silu_f(v);
    }
    __syncthreads();
    {
        float acc[K4_NPB];
#pragma unroll
        for (int nn = 0; nn < K4_NPB; ++nn) acc[nn] = 0.f;
        for (int i4 = 0; i4 < 16; ++i4) {
            float w0 = Wp2[(i4 * 4 + 0) * 512 + o];
            float w1 = Wp2[(i4 * 4 + 1) * 512 + o];
            float w2 = Wp2[(i4 * 4 + 2) * 512 + o];
            float w3 = Wp2[(i4 * 4 + 3) * 512 + o];
#pragma unroll
            for (int nn = 0; nn < K4_NPB; ++nn) {
                float4 xv = *(const float4*)&u_s[nn][i4 * 4];
                acc[nn] = fmaf(xv.x, w0, acc[nn]);
                acc[nn] = fmaf(xv.y, w1, acc[nn]);
                acc[nn] = fmaf(xv.z, w2, acc[nn]);
                acc[nn] = fmaf(xv.w, w3, acc[nn]);
            }
        }
        __syncthreads();
#pragma unroll
        for (int nn = 0; nn < K4_NPB; ++nn) C[nn][o] = acc[nn];
    }
    __syncthreads();
    {
        int nn = tid >> 6, kk = tid & 63;
        int n = n0 + nn;
        float v = bp2[kk];
#pragma unroll
        for (int j = 0; j < 8; ++j) v = fmaf(na_s[nn][j], C[nn][j * 64 + kk], v);
        int bb = batch[n];
        atomicAdd(&pooled[bb * 64 + kk], v);
        if (kk == 0) atomicAdd(&cnt[bb], 1.0f);
    }
}

// ---------------- K7: mean pool finish + final MLP ----------------
__global__ __launch_bounds__(1024) void k_final(
        const float* __restrict__ pooled, const float* __restrict__ cnt,
        const float* __restrict__ Wq1, const float* __restrict__ bq1,
        const float* __restrict__ Wq2, const float* __restrict__ bq2,
        float* __restrict__ out) {
    __shared__ float g[16][64];
    int b = threadIdx.x >> 6, k = threadIdx.x & 63;
    g[b][k] = pooled[b * 64 + k] / fmaxf(cnt[b], 1.0f);
    __syncthreads();
    float acc = bq1[k];
#pragma unroll
    for (int i = 0; i < 64; ++i) acc = fmaf(g[b][i], Wq1[i * 64 + k], acc);
    float v = silu_f(acc) * Wq2[k];
#pragma unroll
    for (int off = 32; off > 0; off >>= 1) v += __shfl_down(v, off, 64);
    if (k == 0) out[b] = v + bq2[0];
}

extern "C" void kernel_launch(void* const* d_in, const int* in_sizes, int n_in,
                              void* d_out, int out_size, void* d_ws, size_t ws_size,
                              hipStream_t stream) {
    const float* x    = (const float*)d_in[0];
    const int*   eidx = (const int*)  d_in[1];
    const float* ea   = (const float*)d_in[2];
    const float* na   = (const float*)d_in[3];
    const float* amf  = (const float*)d_in[4];
    const float* anf  = (const float*)d_in[5];
    const int*   batch= (const int*)  d_in[6];
    const float* W_emb= (const float*)d_in[7];
    const float* b_emb= (const float*)d_in[8];
    const float* Wm1  = (const float*)d_in[9];
    const float* bm1  = (const float*)d_in[10];
    const float* Wm2  = (const float*)d_in[11];
    const float* bm2  = (const float*)d_in[12];
    const float* Wu1  = (const float*)d_in[13];
    const float* bu1  = (const float*)d_in[14];
    const float* Wu2  = (const float*)d_in[15];
    const float* bu2  = (const float*)d_in[16];
    const float* Wp1  = (const float*)d_in[17];
    const float* bp1  = (const float*)d_in[18];
    const float* Wp2  = (const float*)d_in[19];
    const float* bp2  = (const float*)d_in[20];
    const float* Wq1  = (const float*)d_in[21];
    const float* bq1  = (const float*)d_in[22];
    const float* Wq2  = (const float*)d_in[23];
    const float* bq2  = (const float*)d_in[24];

    float* ws = (float*)d_ws;
    float* h      = ws;                         // N*64 fp32
    float* agg    = h + (size_t)N * 64;         // N*64 fp32
    float* pooled = agg + (size_t)N * 64;       // B*64
    float* cnt    = pooled + B * 64;            // B
    __hip_bfloat16* Pb   = (__hip_bfloat16*)(cnt + 64);          // N*1024 bf16 (pad for align)
    __hip_bfloat16* W2hi = Pb + (size_t)N * 1024;                // 2*32768 bf16
    __hip_bfloat16* W2lo = W2hi + 2 * 32768;

    k_embed<<<N / 4, 256, 0, stream>>>(x, anf, na, W_emb, b_emb, h);
    k_w2<<<256, 256, 0, stream>>>(Wm2, W2hi, W2lo);
    for (int l = 0; l < 2; ++l) {
        hipMemsetAsync(agg, 0, (size_t)N * 64 * sizeof(float), stream);
        k_precompute<<<N / K2_NPB, 512, 0, stream>>>(h, anf, Wm1 + (size_t)l * 131 * 512, Pb);
        k_edge<<<E / 128, 256, 0, stream>>>(eidx, ea, amf, Pb,
                                            Wm1 + (size_t)l * 131 * 512, bm1 + l * 64,
                                            W2hi + (size_t)l * 32768, W2lo + (size_t)l * 32768,
                                            bm2 + l * 64, agg);
        k_update<<<N / K4_NPB, 512, 0, stream>>>(anf, na, agg,
                                                 Wu1 + (size_t)l * 129 * 512, bu1 + l * 64,
                                                 Wu2 + (size_t)l * 64 * 512, bu2 + l * 64, h);
    }
    hipMemsetAsync(pooled, 0, (size_t)(B * 64 + B) * sizeof(float), stream);
    k_prepool<<<N / K4_NPB, 512, 0, stream>>>(h, na, batch, Wp1, bp1, Wp2, bp2, pooled, cnt);
    k_final<<<1, 1024, 0, stream>>>(pooled, cnt, Wq1, bq1, Wq2, bq2, (float*)d_out);
}

// Round 4
// 600.143 us; speedup vs baseline: 1.7603x; 1.0672x over previous
//
#include <hip/hip_runtime.h>
#include <hip/hip_bf16.h>
#include <math.h>

// Problem constants
constexpr int N = 10000;
constexpr int E = 160000;
constexpr int B = 16;
constexpr int POOL_CHUNKS = 80;   // 80 * 125 = 10000

typedef short bf16x8 __attribute__((ext_vector_type(8)));
typedef float f32x4 __attribute__((ext_vector_type(4)));

__device__ __forceinline__ float silu_f(float x) {
    return x / (1.0f + __expf(-x));
}

// ---------------- K1: embedding h = TP(concat(x,anf), na, W_emb) + b ----------------
__global__ __launch_bounds__(256) void k_embed(
        const float* __restrict__ x, const float* __restrict__ anf,
        const float* __restrict__ na, const float* __restrict__ W,
        const float* __restrict__ b, float* __restrict__ h) {
    int wv = threadIdx.x >> 6;
    int k = threadIdx.x & 63;
    int n = blockIdx.x * 4 + wv;
    float naR[8];
#pragma unroll
    for (int j = 0; j < 8; ++j) naR[j] = na[n * 8 + j];
    float acc = b[k];
#pragma unroll
    for (int i = 0; i < 17; ++i) {
        float xi = (i < 16) ? x[n * 16 + i] : anf[n];
#pragma unroll
        for (int j = 0; j < 8; ++j)
            acc = fmaf(xi * naR[j], W[(i * 8 + j) * 64 + k], acc);
    }
    h[(size_t)n * 64 + k] = acc;
}

// ---------------- K_w2: z-type B reorder for F=64 inputs: W[l][i][j][k] -> B[(kk*4+nt)*512 + (c*4+q)*8 + j] ----------------
// value = W[l][i=kk*4+q][j][n=nt*16+c].  Launch 256 blocks for 2 layers, 128 for 1 layer.
__global__ __launch_bounds__(256) void k_w2(
        const float* __restrict__ Wsrc,
        __hip_bfloat16* __restrict__ Whi, __hip_bfloat16* __restrict__ Wlo) {
    int idx = blockIdx.x * 256 + threadIdx.x;
    int l = idx >> 15;
    int rem = idx & 32767;
    int kk = rem >> 11;
    int nt = (rem >> 9) & 3;
    int c  = (rem >> 5) & 15;
    int q  = (rem >> 3) & 3;
    int j  = rem & 7;
    int i = kk * 4 + q;
    int k = nt * 16 + c;
    float wv = Wsrc[(size_t)l * 32768 + i * 512 + j * 64 + k];
    __hip_bfloat16 hi = __float2bfloat16(wv);
    Whi[idx] = hi;
    Wlo[idx] = __float2bfloat16(wv - __bfloat162float(hi));
}

// ---------------- K_wu1: z-type B reorder for F_pad=132 (real 129), 2 layers ----------------
__global__ __launch_bounds__(256) void k_wu1(
        const float* __restrict__ Wu1,
        __hip_bfloat16* __restrict__ Whi, __hip_bfloat16* __restrict__ Wlo) {
    int idx = blockIdx.x * 256 + threadIdx.x;    // 2 * 67584
    int l = idx / 67584;
    int rem = idx % 67584;
    int kk = rem / 2048;          // 0..32
    int r2 = rem % 2048;
    int nt = (r2 >> 9) & 3;
    int c  = (r2 >> 5) & 15;
    int q  = (r2 >> 3) & 3;
    int j  = r2 & 7;
    int i = kk * 4 + q;           // 0..131
    float wv = (i < 129) ? Wu1[(size_t)l * 129 * 512 + i * 512 + j * 64 + nt * 16 + c] : 0.f;
    __hip_bfloat16 hi = __float2bfloat16(wv);
    Whi[idx] = hi;
    Wlo[idx] = __float2bfloat16(wv - __bfloat162float(hi));
}

// ---------------- K_wm1p: plain-type B reorder for precompute GEMM: B[i][o], K pad 96, Nout=1024 ----------------
// value: i<65 ? (o<512 ? Wm1[l][i][o] : Wm1[l][65+i][o-512]) : 0
__global__ __launch_bounds__(256) void k_wm1p(
        const float* __restrict__ Wm1,
        __hip_bfloat16* __restrict__ Whi, __hip_bfloat16* __restrict__ Wlo) {
    int idx = blockIdx.x * 256 + threadIdx.x;    // 2 * 98304
    int l = idx / 98304;
    int rem = idx % 98304;
    int kk = rem / 32768;         // 0..2
    int r2 = rem % 32768;
    int nt = (r2 >> 9) & 63;
    int c  = (r2 >> 5) & 15;
    int q  = (r2 >> 3) & 3;
    int t  = r2 & 7;
    int i = kk * 32 + q * 8 + t;  // 0..95
    int o = nt * 16 + c;          // 0..1023
    float wv = 0.f;
    if (i < 65) {
        const float* Wl = Wm1 + (size_t)l * 131 * 512;
        wv = (o < 512) ? Wl[i * 512 + o] : Wl[(65 + i) * 512 + (o - 512)];
    }
    __hip_bfloat16 hi = __float2bfloat16(wv);
    Whi[idx] = hi;
    Wlo[idx] = __float2bfloat16(wv - __bfloat162float(hi));
}

// ---------------- K2: precompute P[n][1024] = ha[n][0:65] @ B  (MFMA, 16 nodes/block) ----------------
__global__ __launch_bounds__(64) void k_pre_mfma(
        const float* __restrict__ h, const float* __restrict__ anf,
        const __hip_bfloat16* __restrict__ Bhi, const __hip_bfloat16* __restrict__ Blo,
        __hip_bfloat16* __restrict__ P) {
    __shared__ __align__(16) __hip_bfloat16 ha_s[16 * 96];
    int tid = threadIdx.x;
    int n0 = blockIdx.x * 16;
    for (int idx = tid; idx < 16 * 96; idx += 64) {
        int r = idx / 96, c = idx % 96;
        int nc = n0 + r; if (nc >= N) nc = N - 1;
        float v = (c < 64) ? h[(size_t)nc * 64 + c] : (c == 64 ? anf[nc] : 0.f);
        ha_s[idx] = __float2bfloat16(v);
    }
    __syncthreads();
    int c16 = tid & 15, q = tid >> 4;
    bf16x8 aF[3];
#pragma unroll
    for (int kk = 0; kk < 3; ++kk)
        aF[kk] = *(const bf16x8*)&ha_s[c16 * 96 + kk * 32 + q * 8];
    int lofs = (c16 * 4 + q) * 8;
    f32x4 zero4 = {0.f, 0.f, 0.f, 0.f};
    for (int ntg = 0; ntg < 8; ++ntg) {
        f32x4 acc[8];
#pragma unroll
        for (int t = 0; t < 8; ++t) acc[t] = zero4;
#pragma unroll
        for (int kk = 0; kk < 3; ++kk) {
#pragma unroll
            for (int nt2 = 0; nt2 < 8; ++nt2) {
                int nt = ntg * 8 + nt2;
                bf16x8 bh = *(const bf16x8*)(Bhi + (size_t)(kk * 64 + nt) * 512 + lofs);
                bf16x8 bl = *(const bf16x8*)(Blo + (size_t)(kk * 64 + nt) * 512 + lofs);
                acc[nt2] = __builtin_amdgcn_mfma_f32_16x16x32_bf16(aF[kk], bh, acc[nt2], 0, 0, 0);
                acc[nt2] = __builtin_amdgcn_mfma_f32_16x16x32_bf16(aF[kk], bl, acc[nt2], 0, 0, 0);
            }
        }
#pragma unroll
        for (int nt2 = 0; nt2 < 8; ++nt2)
#pragma unroll
            for (int r = 0; r < 4; ++r) {
                int n = n0 + q * 4 + r;
                if (n < N)
                    P[(size_t)n * 1024 + (ntg * 8 + nt2) * 16 + c16] = __float2bfloat16(acc[nt2][r]);
            }
    }
}

// ---------------- K3: edge kernel (unchanged from R3 — proven) ----------------
constexpr int MS = 72;
__global__ __launch_bounds__(256, 3) void k_edge(
        const int* __restrict__ eidx, const float* __restrict__ ea,
        const float* __restrict__ amf, const __hip_bfloat16* __restrict__ P,
        const float* __restrict__ Wm1_l, const float* __restrict__ bm1_l,
        const __hip_bfloat16* __restrict__ W2hi, const __hip_bfloat16* __restrict__ W2lo,
        const float* __restrict__ bm2_l, float* __restrict__ agg) {
    __shared__ __align__(16) __hip_bfloat16 m_s[128 * MS];
    __shared__ float ea_s[128][9];
    __shared__ float amf_s[128];
    __shared__ int src_s[128], dst_s[128];
    __shared__ float w130_s[512];
    __shared__ float bm1_s[64], bm2_s[64];
    int tid = threadIdx.x;
    int l = tid & 63, w = tid >> 6;
    int e0 = blockIdx.x * 128;
    for (int idx = tid; idx < 128; idx += 256) {
        src_s[idx] = eidx[e0 + idx];
        dst_s[idx] = eidx[E + e0 + idx];
        amf_s[idx] = amf[e0 + idx];
    }
    for (int idx = tid; idx < 1024; idx += 256) ea_s[idx >> 3][idx & 7] = ea[(size_t)e0 * 8 + idx];
    for (int idx = tid; idx < 512; idx += 256) w130_s[idx] = Wm1_l[130 * 512 + idx];
    if (tid < 64) { bm1_s[tid] = bm1_l[tid]; bm2_s[tid] = bm2_l[tid]; }
    __syncthreads();

    int k = l;
    float bm1k = bm1_s[k];
#pragma unroll 4
    for (int q = 0; q < 32; ++q) {
        int le = w * 32 + q;
        const __hip_bfloat16* P1 = P + (size_t)dst_s[le] * 1024 + k;
        const __hip_bfloat16* P2 = P + (size_t)src_s[le] * 1024 + 512 + k;
        float amfe = amf_s[le];
        float macc = bm1k;
#pragma unroll
        for (int j = 0; j < 8; ++j) {
            float s = __bfloat162float(P1[j * 64]) + __bfloat162float(P2[j * 64]) +
                      amfe * w130_s[j * 64 + k];
            macc = fmaf(ea_s[le][j], s, macc);
        }
        m_s[le * MS + k] = __float2bfloat16(silu_f(macc));
    }
    __syncthreads();

    int c16 = l & 15, q = l >> 4;
    int e0w = w * 32;
    float eaA[2][8];
#pragma unroll
    for (int mt = 0; mt < 2; ++mt)
#pragma unroll
        for (int j = 0; j < 8; ++j) eaA[mt][j] = ea_s[e0w + mt * 16 + c16][j];

    f32x4 acc[2][4];
    f32x4 zero4 = {0.f, 0.f, 0.f, 0.f};
#pragma unroll
    for (int mt = 0; mt < 2; ++mt)
#pragma unroll
        for (int nt = 0; nt < 4; ++nt) acc[mt][nt] = zero4;

    int lofs = (c16 * 4 + q) * 8;
#pragma unroll 2
    for (int kk = 0; kk < 16; ++kk) {
        bf16x8 bh[4], bl[4];
#pragma unroll
        for (int nt = 0; nt < 4; ++nt) {
            int off = (kk * 4 + nt) * 512 + lofs;
            bh[nt] = *(const bf16x8*)(W2hi + off);
            bl[nt] = *(const bf16x8*)(W2lo + off);
        }
#pragma unroll
        for (int mt = 0; mt < 2; ++mt) {
            float mv = __bfloat162float(m_s[(e0w + mt * 16 + c16) * MS + kk * 4 + q]);
            union { bf16x8 v; __hip_bfloat16 h[8]; } au;
#pragma unroll
            for (int j = 0; j < 8; ++j) au.h[j] = __float2bfloat16(mv * eaA[mt][j]);
#pragma unroll
            for (int nt = 0; nt < 4; ++nt) {
                acc[mt][nt] = __builtin_amdgcn_mfma_f32_16x16x32_bf16(au.v, bh[nt], acc[mt][nt], 0, 0, 0);
                acc[mt][nt] = __builtin_amdgcn_mfma_f32_16x16x32_bf16(au.v, bl[nt], acc[mt][nt], 0, 0, 0);
            }
        }
    }
#pragma unroll
    for (int mt = 0; mt < 2; ++mt)
#pragma unroll
        for (int nt = 0; nt < 4; ++nt) {
            int kd = nt * 16 + c16;
            float bias = bm2_s[kd];
#pragma unroll
            for (int r = 0; r < 4; ++r) {
                int e = e0w + mt * 16 + q * 4 + r;
                float v = silu_f(bias + acc[mt][nt][r]);
                atomicAdd(&agg[(size_t)dst_s[e] * 64 + kd], v);
            }
        }
}

// ---------------- K4: node update via fused z-GEMMs (MFMA, 16 nodes/block) ----------------
__global__ __launch_bounds__(64) void k_upd_mfma(
        const float* __restrict__ h_in, const float* __restrict__ anf,
        const float* __restrict__ na, const float* __restrict__ agg,
        const __hip_bfloat16* __restrict__ W1hi, const __hip_bfloat16* __restrict__ W1lo,
        const float* __restrict__ bu1_l,
        const __hip_bfloat16* __restrict__ W2hi_, const __hip_bfloat16* __restrict__ W2lo_,
        const float* __restrict__ bu2_l,
        float* __restrict__ h) {
    __shared__ __align__(16) __hip_bfloat16 xa_s[16 * 136];
    __shared__ __align__(16) __hip_bfloat16 u1_s[16 * 72];
    int tid = threadIdx.x;
    int n0 = blockIdx.x * 16;
    for (int idx = tid; idx < 16 * 132; idx += 64) {
        int r = idx / 132, c = idx % 132;
        int nc = n0 + r; if (nc >= N) nc = N - 1;
        float v;
        if (c < 64) v = h_in[(size_t)nc * 64 + c];
        else if (c == 64) v = anf[nc];
        else if (c < 129) v = agg[(size_t)nc * 64 + (c - 65)];
        else v = 0.f;
        xa_s[r * 136 + c] = __float2bfloat16(v);
    }
    __syncthreads();
    int c16 = tid & 15, q = tid >> 4;
    float naA[8];
    {
        int nc = n0 + c16; if (nc >= N) nc = N - 1;
#pragma unroll
        for (int j = 0; j < 8; ++j) naA[j] = na[(size_t)nc * 8 + j];
    }
    int lofs = (c16 * 4 + q) * 8;
    f32x4 zero4 = {0.f, 0.f, 0.f, 0.f};
    f32x4 acc[4];
#pragma unroll
    for (int nt = 0; nt < 4; ++nt) acc[nt] = zero4;
#pragma unroll 4
    for (int kk = 0; kk < 33; ++kk) {
        bf16x8 bh[4], bl[4];
#pragma unroll
        for (int nt = 0; nt < 4; ++nt) {
            int off = (kk * 4 + nt) * 512 + lofs;
            bh[nt] = *(const bf16x8*)(W1hi + off);
            bl[nt] = *(const bf16x8*)(W1lo + off);
        }
        float mv = __bfloat162float(xa_s[c16 * 136 + kk * 4 + q]);
        union { bf16x8 v; __hip_bfloat16 hx[8]; } au;
#pragma unroll
        for (int j = 0; j < 8; ++j) au.hx[j] = __float2bfloat16(mv * naA[j]);
#pragma unroll
        for (int nt = 0; nt < 4; ++nt) {
            acc[nt] = __builtin_amdgcn_mfma_f32_16x16x32_bf16(au.v, bh[nt], acc[nt], 0, 0, 0);
            acc[nt] = __builtin_amdgcn_mfma_f32_16x16x32_bf16(au.v, bl[nt], acc[nt], 0, 0, 0);
        }
    }
    // u1 = silu(bu1 + acc) -> LDS (D layout: row=q*4+r, col=nt*16+c16)
#pragma unroll
    for (int nt = 0; nt < 4; ++nt) {
        int kd = nt * 16 + c16;
        float bias = bu1_l[kd];
#pragma unroll
        for (int r = 0; r < 4; ++r) {
            int row = q * 4 + r;
            u1_s[row * 72 + kd] = __float2bfloat16(silu_f(bias + acc[nt][r]));
        }
    }
    __syncthreads();
    f32x4 acc2[4];
#pragma unroll
    for (int nt = 0; nt < 4; ++nt) acc2[nt] = zero4;
#pragma unroll 4
    for (int kk = 0; kk < 16; ++kk) {
        bf16x8 bh[4], bl[4];
#pragma unroll
        for (int nt = 0; nt < 4; ++nt) {
            int off = (kk * 4 + nt) * 512 + lofs;
            bh[nt] = *(const bf16x8*)(W2hi_ + off);
            bl[nt] = *(const bf16x8*)(W2lo_ + off);
        }
        float mv = __bfloat162float(u1_s[c16 * 72 + kk * 4 + q]);
        union { bf16x8 v; __hip_bfloat16 hx[8]; } au;
#pragma unroll
        for (int j = 0; j < 8; ++j) au.hx[j] = __float2bfloat16(mv * naA[j]);
#pragma unroll
        for (int nt = 0; nt < 4; ++nt) {
            acc2[nt] = __builtin_amdgcn_mfma_f32_16x16x32_bf16(au.v, bh[nt], acc2[nt], 0, 0, 0);
            acc2[nt] = __builtin_amdgcn_mfma_f32_16x16x32_bf16(au.v, bl[nt], acc2[nt], 0, 0, 0);
        }
    }
#pragma unroll
    for (int nt = 0; nt < 4; ++nt) {
        int kd = nt * 16 + c16;
        float bias = bu2_l[kd];
#pragma unroll
        for (int r = 0; r < 4; ++r) {
            int n = n0 + q * 4 + r;
            if (n < N) h[(size_t)n * 64 + kd] += bias + acc2[nt][r];
        }
    }
}

// ---------------- K6: prepool via fused z-GEMMs -> p2 (MFMA, 16 nodes/block) ----------------
__global__ __launch_bounds__(64) void k_prepool_mfma(
        const float* __restrict__ h, const float* __restrict__ na,
        const __hip_bfloat16* __restrict__ W1hi, const __hip_bfloat16* __restrict__ W1lo,
        const float* __restrict__ bp1,
        const __hip_bfloat16* __restrict__ W2hi_, const __hip_bfloat16* __restrict__ W2lo_,
        const float* __restrict__ bp2,
        float* __restrict__ p2) {
    __shared__ __align__(16) __hip_bfloat16 xa_s[16 * 72];
    __shared__ __align__(16) __hip_bfloat16 u1_s[16 * 72];
    int tid = threadIdx.x;
    int n0 = blockIdx.x * 16;
    for (int idx = tid; idx < 16 * 64; idx += 64) {
        int r = idx >> 6, c = idx & 63;
        int nc = n0 + r; if (nc >= N) nc = N - 1;
        xa_s[r * 72 + c] = __float2bfloat16(h[(size_t)nc * 64 + c]);
    }
    __syncthreads();
    int c16 = tid & 15, q = tid >> 4;
    float naA[8];
    {
        int nc = n0 + c16; if (nc >= N) nc = N - 1;
#pragma unroll
        for (int j = 0; j < 8; ++j) naA[j] = na[(size_t)nc * 8 + j];
    }
    int lofs = (c16 * 4 + q) * 8;
    f32x4 zero4 = {0.f, 0.f, 0.f, 0.f};
    f32x4 acc[4];
#pragma unroll
    for (int nt = 0; nt < 4; ++nt) acc[nt] = zero4;
#pragma unroll 4
    for (int kk = 0; kk < 16; ++kk) {
        bf16x8 bh[4], bl[4];
#pragma unroll
        for (int nt = 0; nt < 4; ++nt) {
            int off = (kk * 4 + nt) * 512 + lofs;
            bh[nt] = *(const bf16x8*)(W1hi + off);
            bl[nt] = *(const bf16x8*)(W1lo + off);
        }
        float mv = __bfloat162float(xa_s[c16 * 72 + kk * 4 + q]);
        union { bf16x8 v; __hip_bfloat16 hx[8]; } au;
#pragma unroll
        for (int j = 0; j < 8; ++j) au.hx[j] = __float2bfloat16(mv * naA[j]);
#pragma unroll
        for (int nt = 0; nt < 4; ++nt) {
            acc[nt] = __builtin_amdgcn_mfma_f32_16x16x32_bf16(au.v, bh[nt], acc[nt], 0, 0, 0);
            acc[nt] = __builtin_amdgcn_mfma_f32_16x16x32_bf16(au.v, bl[nt], acc[nt], 0, 0, 0);
        }
    }
#pragma unroll
    for (int nt = 0; nt < 4; ++nt) {
        int kd = nt * 16 + c16;
        float bias = bp1[kd];
#pragma unroll
        for (int r = 0; r < 4; ++r)
            u1_s[(q * 4 + r) * 72 + kd] = __float2bfloat16(silu_f(bias + acc[nt][r]));
    }
    __syncthreads();
    f32x4 acc2[4];
#pragma unroll
    for (int nt = 0; nt < 4; ++nt) acc2[nt] = zero4;
#pragma unroll 4
    for (int kk = 0; kk < 16; ++kk) {
        bf16x8 bh[4], bl[4];
#pragma unroll
        for (int nt = 0; nt < 4; ++nt) {
            int off = (kk * 4 + nt) * 512 + lofs;
            bh[nt] = *(const bf16x8*)(W2hi_ + off);
            bl[nt] = *(const bf16x8*)(W2lo_ + off);
        }
        float mv = __bfloat162float(u1_s[c16 * 72 + kk * 4 + q]);
        union { bf16x8 v; __hip_bfloat16 hx[8]; } au;
#pragma unroll
        for (int j = 0; j < 8; ++j) au.hx[j] = __float2bfloat16(mv * naA[j]);
#pragma unroll
        for (int nt = 0; nt < 4; ++nt) {
            acc2[nt] = __builtin_amdgcn_mfma_f32_16x16x32_bf16(au.v, bh[nt], acc2[nt], 0, 0, 0);
            acc2[nt] = __builtin_amdgcn_mfma_f32_16x16x32_bf16(au.v, bl[nt], acc2[nt], 0, 0, 0);
        }
    }
#pragma unroll
    for (int nt = 0; nt < 4; ++nt) {
        int kd = nt * 16 + c16;
        float bias = bp2[kd];
#pragma unroll
        for (int r = 0; r < 4; ++r) {
            int n = n0 + q * 4 + r;
            if (n < N) p2[(size_t)n * 64 + kd] = bias + acc2[nt][r];
        }
    }
}

// ---------------- K_pool: per-chunk segmented pooling, no global atomics ----------------
__global__ __launch_bounds__(256) void k_pool(
        const float* __restrict__ p2, const int* __restrict__ batch,
        float* __restrict__ partial_p, float* __restrict__ partial_cnt) {
    __shared__ float acc_s[16 * 64];
    __shared__ float cnt_s[16];
    int tid = threadIdx.x;
    for (int idx = tid; idx < 1024; idx += 256) acc_s[idx] = 0.f;
    if (tid < 16) cnt_s[tid] = 0.f;
    __syncthreads();
    int w = tid >> 6, k = tid & 63;
    int base = blockIdx.x * 125;
    for (int i = 0; i < 32; ++i) {
        int nl = i * 4 + w;
        if (nl < 125) {
            int n = base + nl;
            int b = batch[n];
            atomicAdd(&acc_s[b * 64 + k], p2[(size_t)n * 64 + k]);
            if (k == 0) atomicAdd(&cnt_s[b], 1.0f);
        }
    }
    __syncthreads();
    for (int idx = tid; idx < 1024; idx += 256)
        partial_p[(size_t)blockIdx.x * 1024 + idx] = acc_s[idx];
    if (tid < 16) partial_cnt[blockIdx.x * 16 + tid] = cnt_s[tid];
}

// ---------------- K7: reduce partials, mean, final MLP ----------------
__global__ __launch_bounds__(1024) void k_final(
        const float* __restrict__ partial_p, const float* __restrict__ partial_cnt,
        const float* __restrict__ Wq1, const float* __restrict__ bq1,
        const float* __restrict__ Wq2, const float* __restrict__ bq2,
        float* __restrict__ out) {
    __shared__ float g[16][64];
    int b = threadIdx.x >> 6, k = threadIdx.x & 63;
    float s = 0.f, cc = 0.f;
    for (int c = 0; c < POOL_CHUNKS; ++c) s += partial_p[(size_t)c * 1024 + b * 64 + k];
    for (int c = 0; c < POOL_CHUNKS; ++c) cc += partial_cnt[c * 16 + b];
    g[b][k] = s / fmaxf(cc, 1.0f);
    __syncthreads();
    float acc = bq1[k];
#pragma unroll
    for (int i = 0; i < 64; ++i) acc = fmaf(g[b][i], Wq1[i * 64 + k], acc);
    float v = silu_f(acc) * Wq2[k];
#pragma unroll
    for (int off = 32; off > 0; off >>= 1) v += __shfl_down(v, off, 64);
    if (k == 0) out[b] = v + bq2[0];
}

extern "C" void kernel_launch(void* const* d_in, const int* in_sizes, int n_in,
                              void* d_out, int out_size, void* d_ws, size_t ws_size,
                              hipStream_t stream) {
    const float* x    = (const float*)d_in[0];
    const int*   eidx = (const int*)  d_in[1];
    const float* ea   = (const float*)d_in[2];
    const float* na   = (const float*)d_in[3];
    const float* amf  = (const float*)d_in[4];
    const float* anf  = (const float*)d_in[5];
    const int*   batch= (const int*)  d_in[6];
    const float* W_emb= (const float*)d_in[7];
    const float* b_emb= (const float*)d_in[8];
    const float* Wm1  = (const float*)d_in[9];
    const float* bm1  = (const float*)d_in[10];
    const float* Wm2  = (const float*)d_in[11];
    const float* bm2  = (const float*)d_in[12];
    const float* Wu1  = (const float*)d_in[13];
    const float* bu1  = (const float*)d_in[14];
    const float* Wu2  = (const float*)d_in[15];
    const float* bu2  = (const float*)d_in[16];
    const float* Wp1  = (const float*)d_in[17];
    const float* bp1  = (const float*)d_in[18];
    const float* Wp2  = (const float*)d_in[19];
    const float* bp2  = (const float*)d_in[20];
    const float* Wq1  = (const float*)d_in[21];
    const float* bq1  = (const float*)d_in[22];
    const float* Wq2  = (const float*)d_in[23];
    const float* bq2  = (const float*)d_in[24];

    float* ws = (float*)d_ws;
    float* h      = ws;                           // N*64
    float* agg    = h + (size_t)N * 64;           // N*64
    float* p2     = agg + (size_t)N * 64;         // N*64
    float* part_p = p2 + (size_t)N * 64;          // 80*16*64
    float* part_c = part_p + POOL_CHUNKS * 1024;  // 80*16
    float* fend   = part_c + POOL_CHUNKS * 16;
    __hip_bfloat16* Pb     = (__hip_bfloat16*)fend;          // N*1024
    __hip_bfloat16* W2hi   = Pb + (size_t)N * 1024;          // 2*32768 each below
    __hip_bfloat16* W2lo   = W2hi + 65536;
    __hip_bfloat16* Wu2hi  = W2lo + 65536;
    __hip_bfloat16* Wu2lo  = Wu2hi + 65536;
    __hip_bfloat16* Wp1hi  = Wu2lo + 65536;                  // 32768 each
    __hip_bfloat16* Wp1lo  = Wp1hi + 32768;
    __hip_bfloat16* Wp2hi  = Wp1lo + 32768;
    __hip_bfloat16* Wp2lo  = Wp2hi + 32768;
    __hip_bfloat16* Wu1hi  = Wp2lo + 32768;                  // 2*67584 each
    __hip_bfloat16* Wu1lo  = Wu1hi + 135168;
    __hip_bfloat16* Wm1phi = Wu1lo + 135168;                 // 2*98304 each
    __hip_bfloat16* Wm1plo = Wm1phi + 196608;

    k_embed<<<N / 4, 256, 0, stream>>>(x, anf, na, W_emb, b_emb, h);
    k_w2<<<256, 256, 0, stream>>>(Wm2, W2hi, W2lo);
    k_w2<<<256, 256, 0, stream>>>(Wu2, Wu2hi, Wu2lo);
    k_w2<<<128, 256, 0, stream>>>(Wp1, Wp1hi, Wp1lo);
    k_w2<<<128, 256, 0, stream>>>(Wp2, Wp2hi, Wp2lo);
    k_wu1<<<528, 256, 0, stream>>>(Wu1, Wu1hi, Wu1lo);
    k_wm1p<<<768, 256, 0, stream>>>(Wm1, Wm1phi, Wm1plo);

    for (int l = 0; l < 2; ++l) {
        hipMemsetAsync(agg, 0, (size_t)N * 64 * sizeof(float), stream);
        k_pre_mfma<<<625, 64, 0, stream>>>(h, anf,
                                           Wm1phi + (size_t)l * 98304, Wm1plo + (size_t)l * 98304, Pb);
        k_edge<<<E / 128, 256, 0, stream>>>(eidx, ea, amf, Pb,
                                            Wm1 + (size_t)l * 131 * 512, bm1 + l * 64,
                                            W2hi + (size_t)l * 32768, W2lo + (size_t)l * 32768,
                                            bm2 + l * 64, agg);
        k_upd_mfma<<<625, 64, 0, stream>>>(h, anf, na, agg,
                                           Wu1hi + (size_t)l * 67584, Wu1lo + (size_t)l * 67584,
                                           bu1 + l * 64,
                                           Wu2hi + (size_t)l * 32768, Wu2lo + (size_t)l * 32768,
                                           bu2 + l * 64, h);
    }
    k_prepool_mfma<<<625, 64, 0, stream>>>(h, na, Wp1hi, Wp1lo, bp1, Wp2hi, Wp2lo, bp2, p2);
    k_pool<<<POOL_CHUNKS, 256, 0, stream>>>(p2, batch, part_p, part_c);
    k_final<<<1, 1024, 0, stream>>>(part_p, part_c, Wq1, bq1, Wq2, bq2, (float*)d_out);
}

// Round 5
// 452.705 us; speedup vs baseline: 2.3335x; 1.3257x over previous
//
#include <hip/hip_runtime.h>
#include <hip/hip_bf16.h>
#include <math.h>

// Problem constants
constexpr int N = 10000;
constexpr int E = 160000;
constexpr int B = 16;
constexpr int POOL_CHUNKS = 80;   // 80 * 125 = 10000

typedef short bf16x8 __attribute__((ext_vector_type(8)));
typedef float f32x4 __attribute__((ext_vector_type(4)));

__device__ __forceinline__ float silu_f(float x) {
    return x / (1.0f + __expf(-x));
}

// ---------------- K1: embedding h = TP(concat(x,anf), na, W_emb) + b ----------------
__global__ __launch_bounds__(256) void k_embed(
        const float* __restrict__ x, const float* __restrict__ anf,
        const float* __restrict__ na, const float* __restrict__ W,
        const float* __restrict__ b, float* __restrict__ h) {
    int wv = threadIdx.x >> 6;
    int k = threadIdx.x & 63;
    int n = blockIdx.x * 4 + wv;
    float naR[8];
#pragma unroll
    for (int j = 0; j < 8; ++j) naR[j] = na[n * 8 + j];
    float acc = b[k];
#pragma unroll
    for (int i = 0; i < 17; ++i) {
        float xi = (i < 16) ? x[n * 16 + i] : anf[n];
#pragma unroll
        for (int j = 0; j < 8; ++j)
            acc = fmaf(xi * naR[j], W[(i * 8 + j) * 64 + k], acc);
    }
    h[(size_t)n * 64 + k] = acc;
}

// ---------------- K_w2: z-type B reorder F=64: B[(kk*4+nt)*512 + (c*4+q)*8 + j] = W[l][i=kk*4+q][j][nt*16+c] ----------------
__global__ __launch_bounds__(256) void k_w2(
        const float* __restrict__ Wsrc,
        __hip_bfloat16* __restrict__ Whi, __hip_bfloat16* __restrict__ Wlo) {
    int idx = blockIdx.x * 256 + threadIdx.x;
    int l = idx >> 15;
    int rem = idx & 32767;
    int kk = rem >> 11;
    int nt = (rem >> 9) & 3;
    int c  = (rem >> 5) & 15;
    int q  = (rem >> 3) & 3;
    int j  = rem & 7;
    int i = kk * 4 + q;
    int k = nt * 16 + c;
    float wv = Wsrc[(size_t)l * 32768 + i * 512 + j * 64 + k];
    __hip_bfloat16 hi = __float2bfloat16(wv);
    Whi[idx] = hi;
    Wlo[idx] = __float2bfloat16(wv - __bfloat162float(hi));
}

// ---------------- K_wu1: z-type B reorder for F_pad=132 (real 129), 2 layers ----------------
__global__ __launch_bounds__(256) void k_wu1(
        const float* __restrict__ Wu1,
        __hip_bfloat16* __restrict__ Whi, __hip_bfloat16* __restrict__ Wlo) {
    int idx = blockIdx.x * 256 + threadIdx.x;    // 2 * 67584
    int l = idx / 67584;
    int rem = idx % 67584;
    int kk = rem / 2048;          // 0..32
    int r2 = rem % 2048;
    int nt = (r2 >> 9) & 3;
    int c  = (r2 >> 5) & 15;
    int q  = (r2 >> 3) & 3;
    int j  = r2 & 7;
    int i = kk * 4 + q;           // 0..131
    float wv = (i < 129) ? Wu1[(size_t)l * 129 * 512 + i * 512 + j * 64 + nt * 16 + c] : 0.f;
    __hip_bfloat16 hi = __float2bfloat16(wv);
    Whi[idx] = hi;
    Wlo[idx] = __float2bfloat16(wv - __bfloat162float(hi));
}

// ---------------- K_wm1p: plain B reorder for precompute GEMM, K pad 96, Nout=1024 ----------------
// Storage column col = part*512 + kd*8 + j  (P gets [part][k][j] layout for vectorized edge gathers)
__global__ __launch_bounds__(256) void k_wm1p(
        const float* __restrict__ Wm1,
        __hip_bfloat16* __restrict__ Whi, __hip_bfloat16* __restrict__ Wlo) {
    int idx = blockIdx.x * 256 + threadIdx.x;    // 2 * 98304
    int l = idx / 98304;
    int rem = idx % 98304;
    int kk = rem / 32768;         // 0..2
    int r2 = rem % 32768;
    int nt = (r2 >> 9) & 63;
    int c  = (r2 >> 5) & 15;
    int q  = (r2 >> 3) & 3;
    int t  = r2 & 7;
    int i = kk * 32 + q * 8 + t;  // 0..95
    int col = nt * 16 + c;        // 0..1023  (storage column)
    int part = col >> 9, kd = (col >> 3) & 63, j = col & 7;
    float wv = 0.f;
    if (i < 65)
        wv = Wm1[(size_t)l * 131 * 512 + (size_t)(part ? 65 + i : i) * 512 + j * 64 + kd];
    __hip_bfloat16 hi = __float2bfloat16(wv);
    Whi[idx] = hi;
    Wlo[idx] = __float2bfloat16(wv - __bfloat162float(hi));
}

// ---------------- K2: precompute P[n][1024] = ha[n][0:65] @ B  (MFMA, 16 nodes, 4 waves split Nout) ----------------
__global__ __launch_bounds__(256) void k_pre_mfma(
        const float* __restrict__ h, const float* __restrict__ anf,
        const __hip_bfloat16* __restrict__ Bhi, const __hip_bfloat16* __restrict__ Blo,
        __hip_bfloat16* __restrict__ P) {
    __shared__ __align__(16) __hip_bfloat16 ha_s[16 * 96];
    int tid = threadIdx.x;
    int w = tid >> 6, l = tid & 63;
    int n0 = blockIdx.x * 16;
    for (int idx = tid; idx < 16 * 96; idx += 256) {
        int r = idx / 96, c = idx % 96;
        float v = (c < 64) ? h[(size_t)(n0 + r) * 64 + c] : (c == 64 ? anf[n0 + r] : 0.f);
        ha_s[idx] = __float2bfloat16(v);
    }
    __syncthreads();
    int c16 = l & 15, q = l >> 4;
    bf16x8 aF[3];
#pragma unroll
    for (int kk = 0; kk < 3; ++kk)
        aF[kk] = *(const bf16x8*)&ha_s[c16 * 96 + kk * 32 + q * 8];
    int lofs = (c16 * 4 + q) * 8;
    f32x4 zero4 = {0.f, 0.f, 0.f, 0.f};
#pragma unroll
    for (int ntg = 0; ntg < 2; ++ntg) {
        f32x4 acc[8];
#pragma unroll
        for (int t = 0; t < 8; ++t) acc[t] = zero4;
#pragma unroll
        for (int kk = 0; kk < 3; ++kk) {
#pragma unroll
            for (int nt2 = 0; nt2 < 8; ++nt2) {
                int nt = w * 16 + ntg * 8 + nt2;
                bf16x8 bh = *(const bf16x8*)(Bhi + (size_t)(kk * 64 + nt) * 512 + lofs);
                bf16x8 bl = *(const bf16x8*)(Blo + (size_t)(kk * 64 + nt) * 512 + lofs);
                acc[nt2] = __builtin_amdgcn_mfma_f32_16x16x32_bf16(aF[kk], bh, acc[nt2], 0, 0, 0);
                acc[nt2] = __builtin_amdgcn_mfma_f32_16x16x32_bf16(aF[kk], bl, acc[nt2], 0, 0, 0);
            }
        }
#pragma unroll
        for (int nt2 = 0; nt2 < 8; ++nt2)
#pragma unroll
            for (int r = 0; r < 4; ++r) {
                int n = n0 + q * 4 + r;
                P[(size_t)n * 1024 + (w * 16 + ntg * 8 + nt2) * 16 + c16] = __float2bfloat16(acc[nt2][r]);
            }
    }
}

// ---------------- K3: edge kernel: vectorized m1 (P in [part][k][j]), silu; z-GEMM MFMA m2; silu; scatter ----------------
constexpr int MS = 72;
__global__ __launch_bounds__(256, 3) void k_edge(
        const int* __restrict__ eidx, const float* __restrict__ ea,
        const float* __restrict__ amf, const __hip_bfloat16* __restrict__ P,
        const float* __restrict__ Wm1_l, const float* __restrict__ bm1_l,
        const __hip_bfloat16* __restrict__ W2hi, const __hip_bfloat16* __restrict__ W2lo,
        const float* __restrict__ bm2_l, float* __restrict__ agg) {
    __shared__ __align__(16) __hip_bfloat16 m_s[128 * MS];
    __shared__ float ea_s[128][9];
    __shared__ float amf_s[128];
    __shared__ int src_s[128], dst_s[128];
    __shared__ float bm1_s[64], bm2_s[64];
    int tid = threadIdx.x;
    int l = tid & 63, w = tid >> 6;
    int e0 = blockIdx.x * 128;
    for (int idx = tid; idx < 128; idx += 256) {
        src_s[idx] = eidx[e0 + idx];
        dst_s[idx] = eidx[E + e0 + idx];
        amf_s[idx] = amf[e0 + idx];
    }
    for (int idx = tid; idx < 1024; idx += 256) ea_s[idx >> 3][idx & 7] = ea[(size_t)e0 * 8 + idx];
    if (tid < 64) { bm1_s[tid] = bm1_l[tid]; bm2_s[tid] = bm2_l[tid]; }
    // w130 in registers: lane l holds w130[l][j] = Wm1[130][j*64+l]
    float w130R[8];
#pragma unroll
    for (int j = 0; j < 8; ++j) w130R[j] = Wm1_l[130 * 512 + j * 64 + l];
    __syncthreads();

    // ---- phase 1: m = bf16(silu(m1)), 2 vector loads per edge ----
    float bm1k = bm1_s[l];
#pragma unroll 4
    for (int q = 0; q < 32; ++q) {
        int le = w * 32 + q;
        bf16x8 p1 = *(const bf16x8*)(P + (size_t)dst_s[le] * 1024 + l * 8);
        bf16x8 p2 = *(const bf16x8*)(P + (size_t)src_s[le] * 1024 + 512 + l * 8);
        float amfe = amf_s[le];
        float macc = bm1k;
#pragma unroll
        for (int j = 0; j < 8; ++j) {
            union { short s; __hip_bfloat16 b; } u1c, u2c;
            u1c.s = p1[j]; u2c.s = p2[j];
            float s = __bfloat162float(u1c.b) + __bfloat162float(u2c.b) + amfe * w130R[j];
            macc = fmaf(ea_s[le][j], s, macc);
        }
        m_s[le * MS + l] = __float2bfloat16(silu_f(macc));
    }
    __syncthreads();

    // ---- phase 2: z-GEMM  D[e][kd] = sum_ij (m[e][i]*ea[e][j]) * W2flat[ij][kd] ----
    int c16 = l & 15, q = l >> 4;
    int e0w = w * 32;
    float eaA[2][8];
#pragma unroll
    for (int mt = 0; mt < 2; ++mt)
#pragma unroll
        for (int j = 0; j < 8; ++j) eaA[mt][j] = ea_s[e0w + mt * 16 + c16][j];

    f32x4 acc[2][4];
    f32x4 zero4 = {0.f, 0.f, 0.f, 0.f};
#pragma unroll
    for (int mt = 0; mt < 2; ++mt)
#pragma unroll
        for (int nt = 0; nt < 4; ++nt) acc[mt][nt] = zero4;

    int lofs = (c16 * 4 + q) * 8;
#pragma unroll 2
    for (int kk = 0; kk < 16; ++kk) {
        bf16x8 bh[4], bl[4];
#pragma unroll
        for (int nt = 0; nt < 4; ++nt) {
            int off = (kk * 4 + nt) * 512 + lofs;
            bh[nt] = *(const bf16x8*)(W2hi + off);
            bl[nt] = *(const bf16x8*)(W2lo + off);
        }
#pragma unroll
        for (int mt = 0; mt < 2; ++mt) {
            float mv = __bfloat162float(m_s[(e0w + mt * 16 + c16) * MS + kk * 4 + q]);
            union { bf16x8 v; __hip_bfloat16 h[8]; } au;
#pragma unroll
            for (int j = 0; j < 8; ++j) au.h[j] = __float2bfloat16(mv * eaA[mt][j]);
#pragma unroll
            for (int nt = 0; nt < 4; ++nt) {
                acc[mt][nt] = __builtin_amdgcn_mfma_f32_16x16x32_bf16(au.v, bh[nt], acc[mt][nt], 0, 0, 0);
                acc[mt][nt] = __builtin_amdgcn_mfma_f32_16x16x32_bf16(au.v, bl[nt], acc[mt][nt], 0, 0, 0);
            }
        }
    }
#pragma unroll
    for (int mt = 0; mt < 2; ++mt)
#pragma unroll
        for (int nt = 0; nt < 4; ++nt) {
            int kd = nt * 16 + c16;
            float bias = bm2_s[kd];
#pragma unroll
            for (int r = 0; r < 4; ++r) {
                int e = e0w + mt * 16 + q * 4 + r;
                float v = silu_f(bias + acc[mt][nt][r]);
                atomicAdd(&agg[(size_t)dst_s[e] * 64 + kd], v);
            }
        }
}

// ---------------- K4: node update, fused z-GEMMs, 4 waves split K + LDS reduce ----------------
__global__ __launch_bounds__(256) void k_upd_mfma(
        const float* __restrict__ h_in, const float* __restrict__ anf,
        const float* __restrict__ na, const float* __restrict__ agg,
        const __hip_bfloat16* __restrict__ W1hi, const __hip_bfloat16* __restrict__ W1lo,
        const float* __restrict__ bu1_l,
        const __hip_bfloat16* __restrict__ W2hi_, const __hip_bfloat16* __restrict__ W2lo_,
        const float* __restrict__ bu2_l,
        float* __restrict__ h) {
    __shared__ __align__(16) __hip_bfloat16 xa_s[16 * 136];
    __shared__ __align__(16) __hip_bfloat16 u1_s[16 * 72];
    __shared__ float part_s[4][16][64];
    int tid = threadIdx.x;
    int w = tid >> 6, l = tid & 63;
    int n0 = blockIdx.x * 16;
    for (int idx = tid; idx < 16 * 132; idx += 256) {
        int r = idx / 132, c = idx % 132;
        int n = n0 + r;
        float v;
        if (c < 64) v = h_in[(size_t)n * 64 + c];
        else if (c == 64) v = anf[n];
        else if (c < 129) v = agg[(size_t)n * 64 + (c - 65)];
        else v = 0.f;
        xa_s[r * 136 + c] = __float2bfloat16(v);
    }
    int c16 = l & 15, q = l >> 4;
    float naA[8];
#pragma unroll
    for (int j = 0; j < 8; ++j) naA[j] = na[(size_t)(n0 + c16) * 8 + j];
    __syncthreads();
    int lofs = (c16 * 4 + q) * 8;
    f32x4 zero4 = {0.f, 0.f, 0.f, 0.f};
    f32x4 acc[4];
#pragma unroll
    for (int nt = 0; nt < 4; ++nt) acc[nt] = zero4;
    for (int kk = w; kk < 33; kk += 4) {
        bf16x8 bh[4], bl[4];
#pragma unroll
        for (int nt = 0; nt < 4; ++nt) {
            int off = (kk * 4 + nt) * 512 + lofs;
            bh[nt] = *(const bf16x8*)(W1hi + off);
            bl[nt] = *(const bf16x8*)(W1lo + off);
        }
        float mv = __bfloat162float(xa_s[c16 * 136 + kk * 4 + q]);
        union { bf16x8 v; __hip_bfloat16 hx[8]; } au;
#pragma unroll
        for (int j = 0; j < 8; ++j) au.hx[j] = __float2bfloat16(mv * naA[j]);
#pragma unroll
        for (int nt = 0; nt < 4; ++nt) {
            acc[nt] = __builtin_amdgcn_mfma_f32_16x16x32_bf16(au.v, bh[nt], acc[nt], 0, 0, 0);
            acc[nt] = __builtin_amdgcn_mfma_f32_16x16x32_bf16(au.v, bl[nt], acc[nt], 0, 0, 0);
        }
    }
#pragma unroll
    for (int nt = 0; nt < 4; ++nt)
#pragma unroll
        for (int r = 0; r < 4; ++r) part_s[w][q * 4 + r][nt * 16 + c16] = acc[nt][r];
    __syncthreads();
    for (int t = tid; t < 1024; t += 256) {
        int row = t >> 6, col = t & 63;
        float v = part_s[0][row][col] + part_s[1][row][col] + part_s[2][row][col] +
                  part_s[3][row][col] + bu1_l[col];
        u1_s[row * 72 + col] = __float2bfloat16(silu_f(v));
    }
    __syncthreads();
    f32x4 acc2[4];
#pragma unroll
    for (int nt = 0; nt < 4; ++nt) acc2[nt] = zero4;
    for (int kk = w; kk < 16; kk += 4) {
        bf16x8 bh[4], bl[4];
#pragma unroll
        for (int nt = 0; nt < 4; ++nt) {
            int off = (kk * 4 + nt) * 512 + lofs;
            bh[nt] = *(const bf16x8*)(W2hi_ + off);
            bl[nt] = *(const bf16x8*)(W2lo_ + off);
        }
        float mv = __bfloat162float(u1_s[c16 * 72 + kk * 4 + q]);
        union { bf16x8 v; __hip_bfloat16 hx[8]; } au;
#pragma unroll
        for (int j = 0; j < 8; ++j) au.hx[j] = __float2bfloat16(mv * naA[j]);
#pragma unroll
        for (int nt = 0; nt < 4; ++nt) {
            acc2[nt] = __builtin_amdgcn_mfma_f32_16x16x32_bf16(au.v, bh[nt], acc2[nt], 0, 0, 0);
            acc2[nt] = __builtin_amdgcn_mfma_f32_16x16x32_bf16(au.v, bl[nt], acc2[nt], 0, 0, 0);
        }
    }
    __syncthreads();
#pragma unroll
    for (int nt = 0; nt < 4; ++nt)
#pragma unroll
        for (int r = 0; r < 4; ++r) part_s[w][q * 4 + r][nt * 16 + c16] = acc2[nt][r];
    __syncthreads();
    for (int t = tid; t < 1024; t += 256) {
        int row = t >> 6, col = t & 63;
        float v = part_s[0][row][col] + part_s[1][row][col] + part_s[2][row][col] +
                  part_s[3][row][col] + bu2_l[col];
        h[(size_t)(n0 + row) * 64 + col] += v;
    }
}

// ---------------- K6: prepool, fused z-GEMMs, 4 waves split K + LDS reduce -> p2 ----------------
__global__ __launch_bounds__(256) void k_prepool_mfma(
        const float* __restrict__ h, const float* __restrict__ na,
        const __hip_bfloat16* __restrict__ W1hi, const __hip_bfloat16* __restrict__ W1lo,
        const float* __restrict__ bp1,
        const __hip_bfloat16* __restrict__ W2hi_, const __hip_bfloat16* __restrict__ W2lo_,
        const float* __restrict__ bp2,
        float* __restrict__ p2) {
    __shared__ __align__(16) __hip_bfloat16 xa_s[16 * 72];
    __shared__ __align__(16) __hip_bfloat16 u1_s[16 * 72];
    __shared__ float part_s[4][16][64];
    int tid = threadIdx.x;
    int w = tid >> 6, l = tid & 63;
    int n0 = blockIdx.x * 16;
    for (int idx = tid; idx < 16 * 64; idx += 256) {
        int r = idx >> 6, c = idx & 63;
        xa_s[r * 72 + c] = __float2bfloat16(h[(size_t)(n0 + r) * 64 + c]);
    }
    int c16 = l & 15, q = l >> 4;
    float naA[8];
#pragma unroll
    for (int j = 0; j < 8; ++j) naA[j] = na[(size_t)(n0 + c16) * 8 + j];
    __syncthreads();
    int lofs = (c16 * 4 + q) * 8;
    f32x4 zero4 = {0.f, 0.f, 0.f, 0.f};
    f32x4 acc[4];
#pragma unroll
    for (int nt = 0; nt < 4; ++nt) acc[nt] = zero4;
    for (int kk = w; kk < 16; kk += 4) {
        bf16x8 bh[4], bl[4];
#pragma unroll
        for (int nt = 0; nt < 4; ++nt) {
            int off = (kk * 4 + nt) * 512 + lofs;
            bh[nt] = *(const bf16x8*)(W1hi + off);
            bl[nt] = *(const bf16x8*)(W1lo + off);
        }
        float mv = __bfloat162float(xa_s[c16 * 72 + kk * 4 + q]);
        union { bf16x8 v; __hip_bfloat16 hx[8]; } au;
#pragma unroll
        for (int j = 0; j < 8; ++j) au.hx[j] = __float2bfloat16(mv * naA[j]);
#pragma unroll
        for (int nt = 0; nt < 4; ++nt) {
            acc[nt] = __builtin_amdgcn_mfma_f32_16x16x32_bf16(au.v, bh[nt], acc[nt], 0, 0, 0);
            acc[nt] = __builtin_amdgcn_mfma_f32_16x16x32_bf16(au.v, bl[nt], acc[nt], 0, 0, 0);
        }
    }
#pragma unroll
    for (int nt = 0; nt < 4; ++nt)
#pragma unroll
        for (int r = 0; r < 4; ++r) part_s[w][q * 4 + r][nt * 16 + c16] = acc[nt][r];
    __syncthreads();
    for (int t = tid; t < 1024; t += 256) {
        int row = t >> 6, col = t & 63;
        float v = part_s[0][row][col] + part_s[1][row][col] + part_s[2][row][col] +
                  part_s[3][row][col] + bp1[col];
        u1_s[row * 72 + col] = __float2bfloat16(silu_f(v));
    }
    __syncthreads();
    f32x4 acc2[4];
#pragma unroll
    for (int nt = 0; nt < 4; ++nt) acc2[nt] = zero4;
    for (int kk = w; kk < 16; kk += 4) {
        bf16x8 bh[4], bl[4];
#pragma unroll
        for (int nt = 0; nt < 4; ++nt) {
            int off = (kk * 4 + nt) * 512 + lofs;
            bh[nt] = *(const bf16x8*)(W2hi_ + off);
            bl[nt] = *(const bf16x8*)(W2lo_ + off);
        }
        float mv = __bfloat162float(u1_s[c16 * 72 + kk * 4 + q]);
        union { bf16x8 v; __hip_bfloat16 hx[8]; } au;
#pragma unroll
        for (int j = 0; j < 8; ++j) au.hx[j] = __float2bfloat16(mv * naA[j]);
#pragma unroll
        for (int nt = 0; nt < 4; ++nt) {
            acc2[nt] = __builtin_amdgcn_mfma_f32_16x16x32_bf16(au.v, bh[nt], acc2[nt], 0, 0, 0);
            acc2[nt] = __builtin_amdgcn_mfma_f32_16x16x32_bf16(au.v, bl[nt], acc2[nt], 0, 0, 0);
        }
    }
    __syncthreads();
#pragma unroll
    for (int nt = 0; nt < 4; ++nt)
#pragma unroll
        for (int r = 0; r < 4; ++r) part_s[w][q * 4 + r][nt * 16 + c16] = acc2[nt][r];
    __syncthreads();
    for (int t = tid; t < 1024; t += 256) {
        int row = t >> 6, col = t & 63;
        float v = part_s[0][row][col] + part_s[1][row][col] + part_s[2][row][col] +
                  part_s[3][row][col] + bp2[col];
        p2[(size_t)(n0 + row) * 64 + col] = v;
    }
}

// ---------------- K_pool: per-chunk segmented pooling, no global atomics ----------------
__global__ __launch_bounds__(256) void k_pool(
        const float* __restrict__ p2, const int* __restrict__ batch,
        float* __restrict__ partial_p, float* __restrict__ partial_cnt) {
    __shared__ float acc_s[16 * 64];
    __shared__ float cnt_s[16];
    int tid = threadIdx.x;
    for (int idx = tid; idx < 1024; idx += 256) acc_s[idx] = 0.f;
    if (tid < 16) cnt_s[tid] = 0.f;
    __syncthreads();
    int w = tid >> 6, k = tid & 63;
    int base = blockIdx.x * 125;
    for (int i = 0; i < 32; ++i) {
        int nl = i * 4 + w;
        if (nl < 125) {
            int n = base + nl;
            int b = batch[n];
            atomicAdd(&acc_s[b * 64 + k], p2[(size_t)n * 64 + k]);
            if (k == 0) atomicAdd(&cnt_s[b], 1.0f);
        }
    }
    __syncthreads();
    for (int idx = tid; idx < 1024; idx += 256)
        partial_p[(size_t)blockIdx.x * 1024 + idx] = acc_s[idx];
    if (tid < 16) partial_cnt[blockIdx.x * 16 + tid] = cnt_s[tid];
}

// ---------------- K7: reduce partials, mean, final MLP ----------------
__global__ __launch_bounds__(1024) void k_final(
        const float* __restrict__ partial_p, const float* __restrict__ partial_cnt,
        const float* __restrict__ Wq1, const float* __restrict__ bq1,
        const float* __restrict__ Wq2, const float* __restrict__ bq2,
        float* __restrict__ out) {
    __shared__ float g[16][64];
    int b = threadIdx.x >> 6, k = threadIdx.x & 63;
    float s = 0.f, cc = 0.f;
    for (int c = 0; c < POOL_CHUNKS; ++c) s += partial_p[(size_t)c * 1024 + b * 64 + k];
    for (int c = 0; c < POOL_CHUNKS; ++c) cc += partial_cnt[c * 16 + b];
    g[b][k] = s / fmaxf(cc, 1.0f);
    __syncthreads();
    float acc = bq1[k];
#pragma unroll
    for (int i = 0; i < 64; ++i) acc = fmaf(g[b][i], Wq1[i * 64 + k], acc);
    float v = silu_f(acc) * Wq2[k];
#pragma unroll
    for (int off = 32; off > 0; off >>= 1) v += __shfl_down(v, off, 64);
    if (k == 0) out[b] = v + bq2[0];
}

extern "C" void kernel_launch(void* const* d_in, const int* in_sizes, int n_in,
                              void* d_out, int out_size, void* d_ws, size_t ws_size,
                              hipStream_t stream) {
    const float* x    = (const float*)d_in[0];
    const int*   eidx = (const int*)  d_in[1];
    const float* ea   = (const float*)d_in[2];
    const float* na   = (const float*)d_in[3];
    const float* amf  = (const float*)d_in[4];
    const float* anf  = (const float*)d_in[5];
    const int*   batch= (const int*)  d_in[6];
    const float* W_emb= (const float*)d_in[7];
    const float* b_emb= (const float*)d_in[8];
    const float* Wm1  = (const float*)d_in[9];
    const float* bm1  = (const float*)d_in[10];
    const float* Wm2  = (const float*)d_in[11];
    const float* bm2  = (const float*)d_in[12];
    const float* Wu1  = (const float*)d_in[13];
    const float* bu1  = (const float*)d_in[14];
    const float* Wu2  = (const float*)d_in[15];
    const float* bu2  = (const float*)d_in[16];
    const float* Wp1  = (const float*)d_in[17];
    const float* bp1  = (const float*)d_in[18];
    const float* Wp2  = (const float*)d_in[19];
    const float* bp2  = (const float*)d_in[20];
    const float* Wq1  = (const float*)d_in[21];
    const float* bq1  = (const float*)d_in[22];
    const float* Wq2  = (const float*)d_in[23];
    const float* bq2  = (const float*)d_in[24];

    float* ws = (float*)d_ws;
    float* h      = ws;                           // N*64
    float* agg    = h + (size_t)N * 64;           // N*64
    float* p2     = agg + (size_t)N * 64;         // N*64
    float* part_p = p2 + (size_t)N * 64;          // 80*16*64
    float* part_c = part_p + POOL_CHUNKS * 1024;  // 80*16
    float* fend   = part_c + POOL_CHUNKS * 16;
    __hip_bfloat16* Pb     = (__hip_bfloat16*)fend;          // N*1024
    __hip_bfloat16* W2hi   = Pb + (size_t)N * 1024;
    __hip_bfloat16* W2lo   = W2hi + 65536;
    __hip_bfloat16* Wu2hi  = W2lo + 65536;
    __hip_bfloat16* Wu2lo  = Wu2hi + 65536;
    __hip_bfloat16* Wp1hi  = Wu2lo + 65536;
    __hip_bfloat16* Wp1lo  = Wp1hi + 32768;
    __hip_bfloat16* Wp2hi  = Wp1lo + 32768;
    __hip_bfloat16* Wp2lo  = Wp2hi + 32768;
    __hip_bfloat16* Wu1hi  = Wp2lo + 32768;
    __hip_bfloat16* Wu1lo  = Wu1hi + 135168;
    __hip_bfloat16* Wm1phi = Wu1lo + 135168;
    __hip_bfloat16* Wm1plo = Wm1phi + 196608;

    k_embed<<<N / 4, 256, 0, stream>>>(x, anf, na, W_emb, b_emb, h);
    k_w2<<<256, 256, 0, stream>>>(Wm2, W2hi, W2lo);
    k_w2<<<256, 256, 0, stream>>>(Wu2, Wu2hi, Wu2lo);
    k_w2<<<128, 256, 0, stream>>>(Wp1, Wp1hi, Wp1lo);
    k_w2<<<128, 256, 0, stream>>>(Wp2, Wp2hi, Wp2lo);
    k_wu1<<<528, 256, 0, stream>>>(Wu1, Wu1hi, Wu1lo);
    k_wm1p<<<768, 256, 0, stream>>>(Wm1, Wm1phi, Wm1plo);

    for (int l = 0; l < 2; ++l) {
        hipMemsetAsync(agg, 0, (size_t)N * 64 * sizeof(float), stream);
        k_pre_mfma<<<625, 256, 0, stream>>>(h, anf,
                                            Wm1phi + (size_t)l * 98304, Wm1plo + (size_t)l * 98304, Pb);
        k_edge<<<E / 128, 256, 0, stream>>>(eidx, ea, amf, Pb,
                                            Wm1 + (size_t)l * 131 * 512, bm1 + l * 64,
                                            W2hi + (size_t)l * 32768, W2lo + (size_t)l * 32768,
                                            bm2 + l * 64, agg);
        k_upd_mfma<<<625, 256, 0, stream>>>(h, anf, na, agg,
                                            Wu1hi + (size_t)l * 67584, Wu1lo + (size_t)l * 67584,
                                            bu1 + l * 64,
                                            Wu2hi + (size_t)l * 32768, Wu2lo + (size_t)l * 32768,
                                            bu2 + l * 64, h);
    }
    k_prepool_mfma<<<625, 256, 0, stream>>>(h, na, Wp1hi, Wp1lo, bp1, Wp2hi, Wp2lo, bp2, p2);
    k_pool<<<POOL_CHUNKS, 256, 0, stream>>>(p2, batch, part_p, part_c);
    k_final<<<1, 1024, 0, stream>>>(part_p, part_c, Wq1, bq1, Wq2, bq2, (float*)d_out);
}